// Round 1
// baseline (1806.927 us; speedup 1.0000x reference)
//
#include <hip/hip_runtime.h>
#include <math.h>

#define DEV __device__ __forceinline__

DEV float gelu_f(float x) { return 0.5f * x * (1.f + erff(x * 0.70710678118654752440f)); }
// monotone float->uint encoding for atomicMax on signed floats
DEV unsigned enc_f(float f) { unsigned u = __float_as_uint(f); return (u & 0x80000000u) ? ~u : (u | 0x80000000u); }
DEV float dec_f(unsigned e) { return (e & 0x80000000u) ? __uint_as_float(e ^ 0x80000000u) : __uint_as_float(~e); }

// ---------------- generic f32 tiled GEMM: C[M,N] = act(A[M,K] @ W[N,K]^T + bias) ----------------
// AMODE: 0 = A direct; 1 = A[gidx[m]]*K + abias, then ELU (GAT output gather); 2 = concat(A, A2) at ksplit
// EPI:   0 = none; 1 = exact GELU; 2 = sigmoid
template<int BM, int BN, int BK, int TM, int TN, int EPI, int AMODE>
__global__ __launch_bounds__(256)
void gemm_k(const float* __restrict__ A, const float* __restrict__ A2,
            const int* __restrict__ gidx, const float* __restrict__ abias,
            const float* __restrict__ W, const float* __restrict__ bias,
            float* __restrict__ C, int M, int N, int K, int ksplit)
{
    constexpr int THREADS = (BM / TM) * (BN / TN);
    static_assert(THREADS == 256, "block must be 256 threads");
    __shared__ float As[BK][BM];
    __shared__ float Ws[BK][BN];
    const int tid = threadIdx.x;
    const int tn = tid % (BN / TN);
    const int tm = tid / (BN / TN);
    const int row0 = blockIdx.y * BM;
    const int col0 = blockIdx.x * BN;
    float acc[TM][TN];
#pragma unroll
    for (int i = 0; i < TM; i++)
#pragma unroll
        for (int j = 0; j < TN; j++) acc[i][j] = 0.f;

    for (int k0 = 0; k0 < K; k0 += BK) {
#pragma unroll
        for (int i = 0; i < (BM * BK) / THREADS; i++) {
            int idx = tid + i * THREADS;
            int m = idx / BK, kk = idx % BK;
            int gm = row0 + m, gk = k0 + kk;
            float v = 0.f;
            if (gm < M && gk < K) {
                if (AMODE == 0) v = A[(size_t)gm * K + gk];
                else if (AMODE == 1) { float t = A[(size_t)gidx[gm] * K + gk] + abias[gk]; v = t > 0.f ? t : expf(t) - 1.f; }
                else v = (gk < ksplit) ? A[(size_t)gm * ksplit + gk] : A2[(size_t)gm * (K - ksplit) + (gk - ksplit)];
            }
            As[kk][m] = v;
        }
#pragma unroll
        for (int i = 0; i < (BN * BK) / THREADS; i++) {
            int idx = tid + i * THREADS;
            int n = idx / BK, kk = idx % BK;
            int gn = col0 + n, gk = k0 + kk;
            Ws[kk][n] = (gn < N && gk < K) ? W[(size_t)gn * K + gk] : 0.f;
        }
        __syncthreads();
#pragma unroll
        for (int kk = 0; kk < BK; ++kk) {
            float a[TM], b[TN];
#pragma unroll
            for (int i = 0; i < TM; i++) a[i] = As[kk][tm * TM + i];
#pragma unroll
            for (int j = 0; j < TN; j++) b[j] = Ws[kk][tn * TN + j];
#pragma unroll
            for (int i = 0; i < TM; i++)
#pragma unroll
                for (int j = 0; j < TN; j++) acc[i][j] = fmaf(a[i], b[j], acc[i][j]);
        }
        __syncthreads();
    }
#pragma unroll
    for (int i = 0; i < TM; i++) {
        int gm = row0 + tm * TM + i;
        if (gm >= M) continue;
#pragma unroll
        for (int j = 0; j < TN; j++) {
            int gn = col0 + tn * TN + j;
            if (gn >= N) continue;
            float v = acc[i][j] + (bias ? bias[gn] : 0.f);
            if (EPI == 1) v = gelu_f(v);
            else if (EPI == 2) v = 1.f / (1.f + expf(-v));
            C[(size_t)gm * N + gn] = v;
        }
    }
}

// ---------------- small kernels ----------------

__global__ void init_k(unsigned* amax, float* denom, int* needed, float* scal, int Nn)
{
    int i = blockIdx.x * 256 + threadIdx.x;
    if (i < Nn * 4) { amax[i] = 0x007FFFFFu; /* enc(-inf) */ denom[i] = 0.f; }
    if (i < Nn) needed[i] = 0;
    if (i < 8) scal[i] = 0.f;
}

__global__ void mark_k(const int* __restrict__ nidx, int* __restrict__ needed, int B)
{
    int b = blockIdx.x * 256 + threadIdx.x;
    if (b < B) needed[nidx[b]] = 1;
}

// scal[0] = sum(edge_weight); scal[1+h] = sum_c lin_edge_w[h,c]*att_edge[h,c]
__global__ void prep_k(const float* __restrict__ ew, int E,
                       const float* __restrict__ lew, const float* __restrict__ ae,
                       float* __restrict__ scal)
{
    float s = 0.f;
    for (int i = blockIdx.x * 256 + threadIdx.x; i < E; i += gridDim.x * 256) s += ew[i];
    __shared__ float red[256];
    red[threadIdx.x] = s;
    __syncthreads();
    for (int off = 128; off; off >>= 1) {
        if (threadIdx.x < off) red[threadIdx.x] += red[threadIdx.x + off];
        __syncthreads();
    }
    if (threadIdx.x == 0) atomicAdd(&scal[0], red[0]);
    if (blockIdx.x == 0) {
        int w = threadIdx.x / 64, lane = threadIdx.x % 64;
        float c = 0.f;
        for (int cc = lane; cc < 256; cc += 64) c += lew[w * 256 + cc] * ae[w * 256 + cc];
        for (int off = 32; off; off >>= 1) c += __shfl_down(c, off);
        if (lane == 0) scal[1 + w] = c;
    }
}

// a_src[n,h] = sum_c xp[n,h*256+c]*att_src[h,c]; same for a_dst. one block per node, one wave per head.
__global__ void att_dots_k(const float* __restrict__ xp, const float* __restrict__ asrc_w,
                           const float* __restrict__ adst_w, float* __restrict__ a_src,
                           float* __restrict__ a_dst)
{
    int node = blockIdx.x;
    int w = threadIdx.x / 64, lane = threadIdx.x % 64;
    const float* row = xp + (size_t)node * 1024 + w * 256;
    float s1 = 0.f, s2 = 0.f;
#pragma unroll
    for (int c = lane; c < 256; c += 64) {
        float v = row[c];
        s1 += v * asrc_w[w * 256 + c];
        s2 += v * adst_w[w * 256 + c];
    }
    for (int off = 32; off; off >>= 1) { s1 += __shfl_down(s1, off); s2 += __shfl_down(s2, off); }
    if (lane == 0) { a_src[node * 4 + w] = s1; a_dst[node * 4 + w] = s2; }
}

__global__ void alpha_max_k(const int* __restrict__ ei, const float* __restrict__ ew,
                            const float* __restrict__ scal, const float* __restrict__ a_src,
                            const float* __restrict__ a_dst, const int* __restrict__ needed,
                            float* __restrict__ alpha, unsigned* __restrict__ amax, int E, int Nn)
{
    int e = blockIdx.x * 256 + threadIdx.x;
    if (e >= E + Nn) return;
    int s, d; float ea;
    if (e < E) { s = ei[e]; d = ei[E + e]; ea = ew[e]; }
    else       { s = d = e - E; ea = scal[0] / (float)E; }
    if (!needed[d]) return;
#pragma unroll
    for (int h = 0; h < 4; h++) {
        float al = a_src[s * 4 + h] + a_dst[d * 4 + h] + ea * scal[1 + h];
        al = al > 0.f ? al : 0.2f * al;  // leaky_relu(0.2)
        alpha[(size_t)e * 4 + h] = al;
        atomicMax(&amax[d * 4 + h], enc_f(al));
    }
}

__global__ void exp_denom_k(const int* __restrict__ ei, const int* __restrict__ needed,
                            float* __restrict__ alpha, const unsigned* __restrict__ amax,
                            float* __restrict__ denom, int E, int Nn)
{
    int e = blockIdx.x * 256 + threadIdx.x;
    if (e >= E + Nn) return;
    int d = (e < E) ? ei[E + e] : e - E;
    if (!needed[d]) return;
#pragma unroll
    for (int h = 0; h < 4; h++) {
        float ex = expf(alpha[(size_t)e * 4 + h] - dec_f(amax[d * 4 + h]));
        alpha[(size_t)e * 4 + h] = ex;
        atomicAdd(&denom[d * 4 + h], ex);
    }
}

// one block per edge; 256 threads x float4 = 1024 channels
__global__ void message_k(const int* __restrict__ ei, const int* __restrict__ needed,
                          const float* __restrict__ alpha, const float* __restrict__ denom,
                          const float* __restrict__ xp, float* __restrict__ agg, int E, int Nn)
{
    int e = blockIdx.x;
    int s, d;
    if (e < E) { s = ei[e]; d = ei[E + e]; }
    else       { s = d = e - E; }
    if (!needed[d]) return;
    int x = threadIdx.x * 4;
    int h = x >> 8;
    float coef = alpha[(size_t)e * 4 + h] / denom[d * 4 + h];
    float4 v = *(const float4*)(xp + (size_t)s * 1024 + x);
    float* o = agg + (size_t)d * 1024 + x;
    atomicAdd(o + 0, coef * v.x);
    atomicAdd(o + 1, coef * v.y);
    atomicAdd(o + 2, coef * v.z);
    atomicAdd(o + 3, coef * v.w);
}

__global__ void fuse_k(const float* __restrict__ h_heur, const float* __restrict__ g,
                       const float* __restrict__ h_sem, const float* __restrict__ h_struct,
                       const float* __restrict__ hwp, float* __restrict__ h_fused, int n)
{
    int i = blockIdx.x * 256 + threadIdx.x;
    if (i >= n) return;
    float hw = hwp[0];
    float gg = g[i];
    float hl = gg * h_sem[i] + (1.f - gg) * h_struct[i];
    h_fused[i] = hw * h_heur[i] + (1.f - hw) * hl;
}

// scores[b] = s1[b,:] . sw2 + sb2 ; one wave per row
__global__ void score_k(const float* __restrict__ s1, const float* __restrict__ sw2,
                        const float* __restrict__ sb2, float* __restrict__ out, int B)
{
    int b = blockIdx.x * 4 + threadIdx.x / 64;
    int lane = threadIdx.x % 64;
    if (b >= B) return;
    float4 v = *(const float4*)(s1 + (size_t)b * 256 + lane * 4);
    float4 w = *(const float4*)(sw2 + lane * 4);
    float s = v.x * w.x + v.y * w.y + v.z * w.z + v.w * w.w;
    for (int off = 32; off; off >>= 1) s += __shfl_down(s, off);
    if (lane == 0) out[b] = s + sb2[0];
}

// ---------------- launch ----------------

extern "C" void kernel_launch(void* const* d_in, const int* in_sizes, int n_in,
                              void* d_out, int out_size, void* d_ws, size_t ws_size,
                              hipStream_t stream)
{
    const float* sem      = (const float*)d_in[0];
    const float* gx       = (const float*)d_in[1];
    const int*   ei       = (const int*)d_in[2];
    const float* ew       = (const float*)d_in[3];
    const float* heur     = (const float*)d_in[4];
    const int*   nidx     = (const int*)d_in[5];
    const float* sem_w1   = (const float*)d_in[6];
    const float* sem_b1   = (const float*)d_in[7];
    const float* sem_w2   = (const float*)d_in[8];
    const float* sem_b2   = (const float*)d_in[9];
    const float* lin_w    = (const float*)d_in[10];
    const float* lin_edge = (const float*)d_in[11];
    const float* att_src  = (const float*)d_in[12];
    const float* att_dst  = (const float*)d_in[13];
    const float* att_edge = (const float*)d_in[14];
    const float* gat_bias = (const float*)d_in[15];
    const float* struct_w = (const float*)d_in[16];
    const float* struct_b = (const float*)d_in[17];
    const float* gate_w   = (const float*)d_in[18];
    const float* gate_b   = (const float*)d_in[19];
    const float* heur_w   = (const float*)d_in[20];
    const float* heur_b   = (const float*)d_in[21];
    const float* hwp      = (const float*)d_in[22];
    const float* sw1      = (const float*)d_in[23];
    const float* sb1      = (const float*)d_in[24];
    const float* sw2      = (const float*)d_in[25];
    const float* sb2      = (const float*)d_in[26];
    float* out = (float*)d_out;

    const int DIN = 768, HC = 1024, HID = 256;
    const int B  = in_sizes[0] / (2 * DIN);
    const int Nn = in_sizes[1] / DIN;
    const int E  = in_sizes[3];

    float* ws = (float*)d_ws;
    size_t off = 0;
    auto alloc = [&](size_t n) { float* p = ws + off; off += n; return p; };
    float* xp       = alloc((size_t)Nn * HC);      // x_proj [N,1024]
    float* agg      = alloc((size_t)Nn * HC);      // GAT aggregation [N,1024]
    float* h_sem    = alloc((size_t)B * HID);
    float* h_struct = alloc((size_t)B * HID);
    float* h_heur   = alloc((size_t)B * HID);
    float* gbuf     = alloc((size_t)B * HID);
    float* h_fused  = alloc((size_t)B * HID);
    float* s1       = alloc((size_t)B * HID);      // also sem-MLP hidden tmp
    float* a_src    = alloc((size_t)Nn * 4);
    float* a_dst    = alloc((size_t)Nn * 4);
    float* alphab   = alloc((size_t)(E + Nn) * 4);
    unsigned* amax  = (unsigned*)alloc((size_t)Nn * 4);
    float* denom    = alloc((size_t)Nn * 4);
    int* neededb    = (int*)alloc((size_t)Nn);
    float* scal     = alloc(8);
    (void)ws_size; (void)n_in; (void)out_size;

    hipMemsetAsync(agg, 0, (size_t)Nn * HC * sizeof(float), stream);
    init_k<<<(Nn * 4 + 255) / 256, 256, 0, stream>>>(amax, denom, neededb, scal, Nn);
    mark_k<<<(B + 255) / 256, 256, 0, stream>>>(nidx, neededb, B);
    prep_k<<<256, 256, 0, stream>>>(ew, E, lin_edge, att_edge, scal);

    dim3 g256(HID / 64, B / 64);  // (4, 64) for the B x 256 GEMMs

    // semantic MLP
    gemm_k<64, 64, 16, 4, 4, 1, 0><<<g256, 256, 0, stream>>>(sem, nullptr, nullptr, nullptr, sem_w1, sem_b1, s1, B, HID, 2 * DIN, 0);
    gemm_k<64, 64, 16, 4, 4, 0, 0><<<g256, 256, 0, stream>>>(s1, nullptr, nullptr, nullptr, sem_w2, sem_b2, h_sem, B, HID, HID, 0);

    // x_proj = graph_x @ lin_w^T  (the big one)
    dim3 gxg(HC / 128, (Nn + 127) / 128);
    gemm_k<128, 128, 16, 8, 8, 0, 0><<<gxg, 256, 0, stream>>>(gx, nullptr, nullptr, nullptr, lin_w, nullptr, xp, Nn, HC, DIN, 0);

    att_dots_k<<<Nn, 256, 0, stream>>>(xp, att_src, att_dst, a_src, a_dst);

    int tot = E + Nn;
    alpha_max_k<<<(tot + 255) / 256, 256, 0, stream>>>(ei, ew, scal, a_src, a_dst, neededb, alphab, amax, E, Nn);
    exp_denom_k<<<(tot + 255) / 256, 256, 0, stream>>>(ei, neededb, alphab, amax, denom, E, Nn);
    message_k<<<tot, 256, 0, stream>>>(ei, neededb, alphab, denom, xp, agg, E, Nn);

    // h_struct = gelu( elu(agg[nidx]+gat_bias) @ struct_w^T + struct_b )   (gather+ELU fused into A-load)
    gemm_k<64, 64, 16, 4, 4, 1, 1><<<g256, 256, 0, stream>>>(agg, nullptr, nidx, gat_bias, struct_w, struct_b, h_struct, B, HID, HC, 0);

    // h_heur = gelu(heur @ heur_w^T + heur_b)
    gemm_k<64, 64, 16, 4, 4, 1, 0><<<g256, 256, 0, stream>>>(heur, nullptr, nullptr, nullptr, heur_w, heur_b, h_heur, B, HID, 6, 0);

    // g = sigmoid(concat(h_sem,h_struct) @ gate_w^T + gate_b)
    gemm_k<64, 64, 16, 4, 4, 2, 2><<<g256, 256, 0, stream>>>(h_sem, h_struct, nullptr, nullptr, gate_w, gate_b, gbuf, B, HID, 512, 256);

    fuse_k<<<(B * HID + 255) / 256, 256, 0, stream>>>(h_heur, gbuf, h_sem, h_struct, hwp, h_fused, B * HID);

    // s1 = gelu(h_fused @ sw1^T + sb1)
    gemm_k<64, 64, 16, 4, 4, 1, 0><<<g256, 256, 0, stream>>>(h_fused, nullptr, nullptr, nullptr, sw1, sb1, s1, B, HID, HID, 0);

    score_k<<<B / 4, 256, 0, stream>>>(s1, sw2, sb2, out, B);
}

// Round 2
// 1080.121 us; speedup vs baseline: 1.6729x; 1.6729x over previous
//
#include <hip/hip_runtime.h>
#include <math.h>

#define DEV __device__ __forceinline__

DEV float gelu_f(float x) { return 0.5f * x * (1.f + erff(x * 0.70710678118654752440f)); }

// ---------------- generic f32 tiled GEMM: C[M,N] = act(A[M,K] @ W[N,K]^T + bias) ----------------
// AMODE: 0 = A direct; 1 = A[gidx[m]]*K + abias, then ELU (GAT output gather); 2 = concat(A, A2) at ksplit
// EPI:   0 = none; 1 = exact GELU; 2 = sigmoid
template<int BM, int BN, int BK, int TM, int TN, int EPI, int AMODE>
__global__ __launch_bounds__(256)
void gemm_k(const float* __restrict__ A, const float* __restrict__ A2,
            const int* __restrict__ gidx, const float* __restrict__ abias,
            const float* __restrict__ W, const float* __restrict__ bias,
            float* __restrict__ C, int M, int N, int K, int ksplit)
{
    constexpr int THREADS = (BM / TM) * (BN / TN);
    static_assert(THREADS == 256, "block must be 256 threads");
    __shared__ float As[BK][BM];
    __shared__ float Ws[BK][BN];
    const int tid = threadIdx.x;
    const int tn = tid % (BN / TN);
    const int tm = tid / (BN / TN);
    const int row0 = blockIdx.y * BM;
    const int col0 = blockIdx.x * BN;
    float acc[TM][TN];
#pragma unroll
    for (int i = 0; i < TM; i++)
#pragma unroll
        for (int j = 0; j < TN; j++) acc[i][j] = 0.f;

    for (int k0 = 0; k0 < K; k0 += BK) {
#pragma unroll
        for (int i = 0; i < (BM * BK) / THREADS; i++) {
            int idx = tid + i * THREADS;
            int m = idx / BK, kk = idx % BK;
            int gm = row0 + m, gk = k0 + kk;
            float v = 0.f;
            if (gm < M && gk < K) {
                if (AMODE == 0) v = A[(size_t)gm * K + gk];
                else if (AMODE == 1) { float t = A[(size_t)gidx[gm] * K + gk] + abias[gk]; v = t > 0.f ? t : expf(t) - 1.f; }
                else v = (gk < ksplit) ? A[(size_t)gm * ksplit + gk] : A2[(size_t)gm * (K - ksplit) + (gk - ksplit)];
            }
            As[kk][m] = v;
        }
#pragma unroll
        for (int i = 0; i < (BN * BK) / THREADS; i++) {
            int idx = tid + i * THREADS;
            int n = idx / BK, kk = idx % BK;
            int gn = col0 + n, gk = k0 + kk;
            Ws[kk][n] = (gn < N && gk < K) ? W[(size_t)gn * K + gk] : 0.f;
        }
        __syncthreads();
#pragma unroll
        for (int kk = 0; kk < BK; ++kk) {
            float a[TM], b[TN];
#pragma unroll
            for (int i = 0; i < TM; i++) a[i] = As[kk][tm * TM + i];
#pragma unroll
            for (int j = 0; j < TN; j++) b[j] = Ws[kk][tn * TN + j];
#pragma unroll
            for (int i = 0; i < TM; i++)
#pragma unroll
                for (int j = 0; j < TN; j++) acc[i][j] = fmaf(a[i], b[j], acc[i][j]);
        }
        __syncthreads();
    }
#pragma unroll
    for (int i = 0; i < TM; i++) {
        int gm = row0 + tm * TM + i;
        if (gm >= M) continue;
#pragma unroll
        for (int j = 0; j < TN; j++) {
            int gn = col0 + tn * TN + j;
            if (gn >= N) continue;
            float v = acc[i][j] + (bias ? bias[gn] : 0.f);
            if (EPI == 1) v = gelu_f(v);
            else if (EPI == 2) v = 1.f / (1.f + expf(-v));
            C[(size_t)gm * N + gn] = v;
        }
    }
}

// ---------------- small kernels ----------------

__global__ void init_k(int* count, int* needed, float* scal, int Nn)
{
    int i = blockIdx.x * 256 + threadIdx.x;
    if (i < Nn) { count[i] = 0; needed[i] = 0; }
    if (i < 8) scal[i] = 0.f;
}

__global__ void mark_k(const int* __restrict__ nidx, int* __restrict__ needed, int B)
{
    int b = blockIdx.x * 256 + threadIdx.x;
    if (b < B) needed[nidx[b]] = 1;
}

// scal[0] = sum(edge_weight); scal[1+h] = sum_c lin_edge_w[h,c]*att_edge[h,c]
__global__ void prep_k(const float* __restrict__ ew, int E,
                       const float* __restrict__ lew, const float* __restrict__ ae,
                       float* __restrict__ scal)
{
    float s = 0.f;
    for (int i = blockIdx.x * 256 + threadIdx.x; i < E; i += gridDim.x * 256) s += ew[i];
    __shared__ float red[256];
    red[threadIdx.x] = s;
    __syncthreads();
    for (int off = 128; off; off >>= 1) {
        if (threadIdx.x < off) red[threadIdx.x] += red[threadIdx.x + off];
        __syncthreads();
    }
    if (threadIdx.x == 0) atomicAdd(&scal[0], red[0]);
    if (blockIdx.x == 0) {
        int w = threadIdx.x / 64, lane = threadIdx.x % 64;
        float c = 0.f;
        for (int cc = lane; cc < 256; cc += 64) c += lew[w * 256 + cc] * ae[w * 256 + cc];
        for (int off = 32; off; off >>= 1) c += __shfl_down(c, off);
        if (lane == 0) scal[1 + w] = c;
    }
}

// a_src[n,h] = sum_c xp[n,h*256+c]*att_src[h,c]; same for a_dst. one block per node, one wave per head.
__global__ void att_dots_k(const float* __restrict__ xp, const float* __restrict__ asrc_w,
                           const float* __restrict__ adst_w, float* __restrict__ a_src,
                           float* __restrict__ a_dst)
{
    int node = blockIdx.x;
    int w = threadIdx.x / 64, lane = threadIdx.x % 64;
    const float* row = xp + (size_t)node * 1024 + w * 256;
    float s1 = 0.f, s2 = 0.f;
#pragma unroll
    for (int c = lane; c < 256; c += 64) {
        float v = row[c];
        s1 += v * asrc_w[w * 256 + c];
        s2 += v * adst_w[w * 256 + c];
    }
    for (int off = 32; off; off >>= 1) { s1 += __shfl_down(s1, off); s2 += __shfl_down(s2, off); }
    if (lane == 0) { a_src[node * 4 + w] = s1; a_dst[node * 4 + w] = s2; }
}

// in-degree counts for needed dst nodes (edges + self loops)
__global__ void count_k(const int* __restrict__ ei, const int* __restrict__ needed,
                        int* __restrict__ count, int E, int Nn)
{
    int e = blockIdx.x * 256 + threadIdx.x;
    if (e >= E + Nn) return;
    int d = (e < E) ? ei[E + e] : e - E;
    if (needed[d]) atomicAdd(&count[d], 1);
}

// single-block exclusive scan: offs[i] = sum_{j<i} count[j]
__global__ __launch_bounds__(1024) void scan_k(const int* __restrict__ count, int* __restrict__ offs, int Nn)
{
    __shared__ int buf[1024];
    __shared__ int carry;
    int t = threadIdx.x;
    if (t == 0) carry = 0;
    __syncthreads();
    for (int base = 0; base < Nn; base += 1024) {
        int v = (base + t < Nn) ? count[base + t] : 0;
        buf[t] = v;
        __syncthreads();
        for (int off = 1; off < 1024; off <<= 1) {
            int add = (t >= off) ? buf[t - off] : 0;
            __syncthreads();
            buf[t] += add;
            __syncthreads();
        }
        if (base + t < Nn) offs[base + t] = carry + buf[t] - v;
        __syncthreads();
        if (t == 0) carry += buf[1023];
        __syncthreads();
    }
}

// scatter edge ids into per-dst CSR lists; offs[d] ends at list end
__global__ void fill_k(const int* __restrict__ ei, const int* __restrict__ needed,
                       int* __restrict__ offs, int* __restrict__ eid, int E, int Nn)
{
    int e = blockIdx.x * 256 + threadIdx.x;
    if (e >= E + Nn) return;
    int d = (e < E) ? ei[E + e] : e - E;
    if (!needed[d]) return;
    int p = atomicAdd(&offs[d], 1);
    eid[p] = e;
}

// fused GAT softmax + aggregation: one block per dst node, 256 threads x float4 = 1024 channels.
#define CH 256
__global__ __launch_bounds__(256)
void gat_agg_k(const int* __restrict__ ei, const float* __restrict__ ew,
               const float* __restrict__ scal, const float* __restrict__ a_src,
               const float* __restrict__ a_dst, const int* __restrict__ needed,
               const int* __restrict__ count, const int* __restrict__ offs_end,
               const int* __restrict__ eid, const float* __restrict__ xp,
               float* __restrict__ agg, int E, int Nn)
{
    int d = blockIdx.x;
    if (!needed[d]) return;
    int c = count[d];
    int start = offs_end[d] - c;
    int tid = threadIdx.x;
    __shared__ int   srcs[CH];
    __shared__ float al[CH * 4];
    __shared__ float mrun[4], drun[4], scale[4];
    if (tid < 4) { mrun[tid] = -1e30f; drun[tid] = 0.f; }
    float4 acc = make_float4(0.f, 0.f, 0.f, 0.f);
    const int h = tid >> 6;               // head of this thread's 4 channels
    const int x = tid * 4;
    const float adst0 = a_dst[d * 4 + 0], adst1 = a_dst[d * 4 + 1],
                adst2 = a_dst[d * 4 + 2], adst3 = a_dst[d * 4 + 3];

    for (int cb = 0; cb < c; cb += CH) {
        int cc = min(CH, c - cb);
        __syncthreads();  // previous chunk's acc readers done with al/srcs
        for (int t = tid; t < cc * 4; t += 256) {
            int j = t >> 2, hh = t & 3;
            int e = eid[start + cb + j];
            int s; float ea;
            if (e < E) { s = ei[e]; ea = ew[e]; }
            else       { s = e - E; ea = scal[0] / (float)E; }
            float ad = hh == 0 ? adst0 : hh == 1 ? adst1 : hh == 2 ? adst2 : adst3;
            float a = a_src[s * 4 + hh] + ad + ea * scal[1 + hh];
            a = a > 0.f ? a : 0.2f * a;   // leaky_relu(0.2)
            al[j * 4 + hh] = a;
            if (hh == 0) srcs[j] = s;
        }
        __syncthreads();
        if (tid < 4) {                    // per-head chunk max + online rescale factors
            float m = -1e30f;
            for (int j = 0; j < cc; j++) m = fmaxf(m, al[j * 4 + tid]);
            float nm = fmaxf(mrun[tid], m);
            float sc = expf(mrun[tid] - nm);
            scale[tid] = sc;
            drun[tid] *= sc;
            mrun[tid] = nm;
        }
        __syncthreads();
        for (int t = tid; t < cc * 4; t += 256) {
            int j = t >> 2, hh = t & 3;
            al[j * 4 + hh] = expf(al[j * 4 + hh] - mrun[hh]);
        }
        __syncthreads();
        if (tid < 4) {
            float s = 0.f;
            for (int j = 0; j < cc; j++) s += al[j * 4 + tid];
            drun[tid] += s;
        }
        // acc update: al ready (sync above), scale ready (two syncs ago)
        float sc = scale[h];
        acc.x *= sc; acc.y *= sc; acc.z *= sc; acc.w *= sc;
        for (int j = 0; j < cc; j++) {
            float w = al[j * 4 + h];
            const float4 v = *(const float4*)(xp + (size_t)srcs[j] * 1024 + x);
            acc.x = fmaf(w, v.x, acc.x);
            acc.y = fmaf(w, v.y, acc.y);
            acc.z = fmaf(w, v.z, acc.z);
            acc.w = fmaf(w, v.w, acc.w);
        }
    }
    __syncthreads();                      // drun final
    float dn = drun[h];
    float4 o = make_float4(acc.x / dn, acc.y / dn, acc.z / dn, acc.w / dn);
    *(float4*)(agg + (size_t)d * 1024 + x) = o;
}

__global__ void fuse_k(const float* __restrict__ h_heur, const float* __restrict__ g,
                       const float* __restrict__ h_sem, const float* __restrict__ h_struct,
                       const float* __restrict__ hwp, float* __restrict__ h_fused, int n)
{
    int i = blockIdx.x * 256 + threadIdx.x;
    if (i >= n) return;
    float hw = hwp[0];
    float gg = g[i];
    float hl = gg * h_sem[i] + (1.f - gg) * h_struct[i];
    h_fused[i] = hw * h_heur[i] + (1.f - hw) * hl;
}

// scores[b] = s1[b,:] . sw2 + sb2 ; one wave per row
__global__ void score_k(const float* __restrict__ s1, const float* __restrict__ sw2,
                        const float* __restrict__ sb2, float* __restrict__ out, int B)
{
    int b = blockIdx.x * 4 + threadIdx.x / 64;
    int lane = threadIdx.x % 64;
    if (b >= B) return;
    float4 v = *(const float4*)(s1 + (size_t)b * 256 + lane * 4);
    float4 w = *(const float4*)(sw2 + lane * 4);
    float s = v.x * w.x + v.y * w.y + v.z * w.z + v.w * w.w;
    for (int off = 32; off; off >>= 1) s += __shfl_down(s, off);
    if (lane == 0) out[b] = s + sb2[0];
}

// ---------------- launch ----------------

extern "C" void kernel_launch(void* const* d_in, const int* in_sizes, int n_in,
                              void* d_out, int out_size, void* d_ws, size_t ws_size,
                              hipStream_t stream)
{
    const float* sem      = (const float*)d_in[0];
    const float* gx       = (const float*)d_in[1];
    const int*   ei       = (const int*)d_in[2];
    const float* ew       = (const float*)d_in[3];
    const float* heur     = (const float*)d_in[4];
    const int*   nidx     = (const int*)d_in[5];
    const float* sem_w1   = (const float*)d_in[6];
    const float* sem_b1   = (const float*)d_in[7];
    const float* sem_w2   = (const float*)d_in[8];
    const float* sem_b2   = (const float*)d_in[9];
    const float* lin_w    = (const float*)d_in[10];
    const float* lin_edge = (const float*)d_in[11];
    const float* att_src  = (const float*)d_in[12];
    const float* att_dst  = (const float*)d_in[13];
    const float* att_edge = (const float*)d_in[14];
    const float* gat_bias = (const float*)d_in[15];
    const float* struct_w = (const float*)d_in[16];
    const float* struct_b = (const float*)d_in[17];
    const float* gate_w   = (const float*)d_in[18];
    const float* gate_b   = (const float*)d_in[19];
    const float* heur_w   = (const float*)d_in[20];
    const float* heur_b   = (const float*)d_in[21];
    const float* hwp      = (const float*)d_in[22];
    const float* sw1      = (const float*)d_in[23];
    const float* sb1      = (const float*)d_in[24];
    const float* sw2      = (const float*)d_in[25];
    const float* sb2      = (const float*)d_in[26];
    float* out = (float*)d_out;

    const int DIN = 768, HC = 1024, HID = 256;
    const int B  = in_sizes[0] / (2 * DIN);
    const int Nn = in_sizes[1] / DIN;
    const int E  = in_sizes[3];

    float* ws = (float*)d_ws;
    size_t off = 0;
    auto alloc = [&](size_t n) { float* p = ws + off; off += n; return p; };
    float* xp       = alloc((size_t)Nn * HC);      // x_proj [N,1024]
    float* agg      = alloc((size_t)Nn * HC);      // GAT aggregation [N,1024]
    float* h_sem    = alloc((size_t)B * HID);
    float* h_struct = alloc((size_t)B * HID);
    float* h_heur   = alloc((size_t)B * HID);
    float* gbuf     = alloc((size_t)B * HID);
    float* h_fused  = alloc((size_t)B * HID);
    float* s1       = alloc((size_t)B * HID);      // also sem-MLP hidden tmp
    float* a_src    = alloc((size_t)Nn * 4);
    float* a_dst    = alloc((size_t)Nn * 4);
    int* countb     = (int*)alloc((size_t)Nn);
    int* offsb      = (int*)alloc((size_t)Nn);
    int* neededb    = (int*)alloc((size_t)Nn);
    int* eidb       = (int*)alloc((size_t)(E + Nn));
    float* scal     = alloc(8);
    (void)ws_size; (void)n_in; (void)out_size;

    init_k<<<(Nn + 255) / 256, 256, 0, stream>>>(countb, neededb, scal, Nn);
    mark_k<<<(B + 255) / 256, 256, 0, stream>>>(nidx, neededb, B);
    prep_k<<<256, 256, 0, stream>>>(ew, E, lin_edge, att_edge, scal);

    int tot = E + Nn;
    count_k<<<(tot + 255) / 256, 256, 0, stream>>>(ei, neededb, countb, E, Nn);
    scan_k<<<1, 1024, 0, stream>>>(countb, offsb, Nn);
    fill_k<<<(tot + 255) / 256, 256, 0, stream>>>(ei, neededb, offsb, eidb, E, Nn);

    dim3 g256(HID / 64, B / 64);  // (4, 64) for the B x 256 GEMMs

    // semantic MLP
    gemm_k<64, 64, 16, 4, 4, 1, 0><<<g256, 256, 0, stream>>>(sem, nullptr, nullptr, nullptr, sem_w1, sem_b1, s1, B, HID, 2 * DIN, 0);
    gemm_k<64, 64, 16, 4, 4, 0, 0><<<g256, 256, 0, stream>>>(s1, nullptr, nullptr, nullptr, sem_w2, sem_b2, h_sem, B, HID, HID, 0);

    // x_proj = graph_x @ lin_w^T  (the big one)
    dim3 gxg(HC / 128, (Nn + 127) / 128);
    gemm_k<128, 128, 16, 8, 8, 0, 0><<<gxg, 256, 0, stream>>>(gx, nullptr, nullptr, nullptr, lin_w, nullptr, xp, Nn, HC, DIN, 0);

    att_dots_k<<<Nn, 256, 0, stream>>>(xp, att_src, att_dst, a_src, a_dst);

    // fused softmax + aggregation over dst-CSR
    gat_agg_k<<<Nn, 256, 0, stream>>>(ei, ew, scal, a_src, a_dst, neededb, countb, offsb, eidb, xp, agg, E, Nn);

    // h_struct = gelu( elu(agg[nidx]+gat_bias) @ struct_w^T + struct_b )   (gather+ELU fused into A-load)
    gemm_k<64, 64, 16, 4, 4, 1, 1><<<g256, 256, 0, stream>>>(agg, nullptr, nidx, gat_bias, struct_w, struct_b, h_struct, B, HID, HC, 0);

    // h_heur = gelu(heur @ heur_w^T + heur_b)
    gemm_k<64, 64, 16, 4, 4, 1, 0><<<g256, 256, 0, stream>>>(heur, nullptr, nullptr, nullptr, heur_w, heur_b, h_heur, B, HID, 6, 0);

    // g = sigmoid(concat(h_sem,h_struct) @ gate_w^T + gate_b)
    gemm_k<64, 64, 16, 4, 4, 2, 2><<<g256, 256, 0, stream>>>(h_sem, h_struct, nullptr, nullptr, gate_w, gate_b, gbuf, B, HID, 512, 256);

    fuse_k<<<(B * HID + 255) / 256, 256, 0, stream>>>(h_heur, gbuf, h_sem, h_struct, hwp, h_fused, B * HID);

    // s1 = gelu(h_fused @ sw1^T + sb1)
    gemm_k<64, 64, 16, 4, 4, 1, 0><<<g256, 256, 0, stream>>>(h_fused, nullptr, nullptr, nullptr, sw1, sb1, s1, B, HID, HID, 0);

    score_k<<<B / 4, 256, 0, stream>>>(s1, sw2, sb2, out, B);
}

// Round 3
// 513.580 us; speedup vs baseline: 3.5183x; 2.1031x over previous
//
#include <hip/hip_runtime.h>
#include <math.h>

#define DEV __device__ __forceinline__

typedef __attribute__((ext_vector_type(8))) short bf16x8;
typedef __attribute__((ext_vector_type(4))) float f32x4;

DEV float gelu_f(float x) { return 0.5f * x * (1.f + erff(x * 0.70710678118654752440f)); }

DEV unsigned short f2bf(float f) {
    unsigned u = __float_as_uint(f);
    u += 0x7FFF + ((u >> 16) & 1);
    return (unsigned short)(u >> 16);
}
DEV float bf2f(unsigned short h) { return __uint_as_float(((unsigned)h) << 16); }
DEV void split2(float v, unsigned short& h, unsigned short& l) {
    h = f2bf(v);
    l = f2bf(v - bf2f(h));
}

// ---------------- split-bf16 MFMA GEMM: C[M,N] = act(A[M,K] @ W[N,K]^T + bias) ----------------
// A,W given as bf16 hi/lo pairs (row-major, K contiguous). No LDS: fragments loaded
// directly from global (L2/L3-resident). GATHER: A row m -> gidx[m].
// EPI: 0 none, 1 exact GELU, 2 sigmoid.
template<int FM, int FN, int WROWS, int WCOLS, int EPI, int GATHER>
__global__ __launch_bounds__(WROWS* WCOLS * 64)
void mgemm_k(const unsigned short* __restrict__ Ah, const unsigned short* __restrict__ Al,
             const int* __restrict__ gidx,
             const unsigned short* __restrict__ Wh, const unsigned short* __restrict__ Wl,
             const float* __restrict__ bias, float* __restrict__ C,
             int M, int N, int K)
{
    constexpr int BM = WROWS * FM * 16, BN = WCOLS * FN * 16;
    const int tid = threadIdx.x;
    const int lane = tid & 63;
    const int wid = tid >> 6;
    const int wr = wid / WCOLS, wc = wid % WCOLS;
    const int brow = blockIdx.y * BM + wr * FM * 16;
    const int bcol = blockIdx.x * BN + wc * FN * 16;
    const int fr = lane & 15;          // A-row / B-col within fragment
    const int kg = (lane >> 4) * 8;    // k sub-offset within 32

    f32x4 acc[FM][FN];
#pragma unroll
    for (int i = 0; i < FM; i++)
#pragma unroll
        for (int j = 0; j < FN; j++) acc[i][j] = (f32x4){0.f, 0.f, 0.f, 0.f};

    const unsigned short* aph[FM];
    const unsigned short* apl[FM];
#pragma unroll
    for (int i = 0; i < FM; i++) {
        int r = brow + i * 16 + fr;
        r = r < M ? r : M - 1;
        if (GATHER) r = gidx[r];
        aph[i] = Ah + (size_t)r * K + kg;
        apl[i] = Al + (size_t)r * K + kg;
    }
    const unsigned short* bph[FN];
    const unsigned short* bpl[FN];
#pragma unroll
    for (int j = 0; j < FN; j++) {
        int c = bcol + j * 16 + fr;
        bph[j] = Wh + (size_t)c * K + kg;
        bpl[j] = Wl + (size_t)c * K + kg;
    }

#pragma unroll 2
    for (int k0 = 0; k0 < K; k0 += 32) {
        bf16x8 ah[FM], al[FM], bh[FN], bl[FN];
#pragma unroll
        for (int i = 0; i < FM; i++) {
            ah[i] = *(const bf16x8*)(aph[i] + k0);
            al[i] = *(const bf16x8*)(apl[i] + k0);
        }
#pragma unroll
        for (int j = 0; j < FN; j++) {
            bh[j] = *(const bf16x8*)(bph[j] + k0);
            bl[j] = *(const bf16x8*)(bpl[j] + k0);
        }
#pragma unroll
        for (int i = 0; i < FM; i++)
#pragma unroll
            for (int j = 0; j < FN; j++) {
                acc[i][j] = __builtin_amdgcn_mfma_f32_16x16x32_bf16(ah[i], bh[j], acc[i][j], 0, 0, 0);
                acc[i][j] = __builtin_amdgcn_mfma_f32_16x16x32_bf16(al[i], bh[j], acc[i][j], 0, 0, 0);
                acc[i][j] = __builtin_amdgcn_mfma_f32_16x16x32_bf16(ah[i], bl[j], acc[i][j], 0, 0, 0);
            }
    }

    const int r0 = (lane >> 4) * 4;    // C/D: col = lane&15, row = (lane>>4)*4 + reg
#pragma unroll
    for (int i = 0; i < FM; i++) {
#pragma unroll
        for (int jj = 0; jj < 4; jj++) {
            int gr = brow + i * 16 + r0 + jj;
            if (gr >= M) continue;
#pragma unroll
            for (int j = 0; j < FN; j++) {
                int gc = bcol + j * 16 + fr;
                float v = acc[i][j][jj] + (bias ? bias[gc] : 0.f);
                if (EPI == 1) v = gelu_f(v);
                else if (EPI == 2) v = 1.f / (1.f + expf(-v));
                C[(size_t)gr * N + gc] = v;
            }
        }
    }
}

// ---------------- conversion kernels ----------------

__global__ void cvt_k(const float* __restrict__ src, unsigned short* __restrict__ hi,
                      unsigned short* __restrict__ lo, int n4)
{
    int i = blockIdx.x * 256 + threadIdx.x;
    if (i >= n4) return;
    float4 v = ((const float4*)src)[i];
    ushort4 h, l;
    split2(v.x, h.x, l.x);
    split2(v.y, h.y, l.y);
    split2(v.z, h.z, l.z);
    split2(v.w, h.w, l.w);
    ((ushort4*)hi)[i] = h;
    ((ushort4*)lo)[i] = l;
}

// concat(h_sem, h_struct) [B,512] -> hi/lo
__global__ void cvt_concat_k(const float* __restrict__ a, const float* __restrict__ b,
                             unsigned short* __restrict__ hi, unsigned short* __restrict__ lo, int B)
{
    int i = blockIdx.x * 256 + threadIdx.x;
    if (i >= B * 128) return;  // groups of 4 cols
    int row = i >> 7, g = i & 127;
    const float* src = (g < 64) ? a + (size_t)row * 256 + g * 4 : b + (size_t)row * 256 + (g - 64) * 4;
    float4 v = *(const float4*)src;
    ushort4 h, l;
    split2(v.x, h.x, l.x);
    split2(v.y, h.y, l.y);
    split2(v.z, h.z, l.z);
    split2(v.w, h.w, l.w);
    ((ushort4*)hi)[i] = h;
    ((ushort4*)lo)[i] = l;
}

// ---------------- setup / graph kernels ----------------

__global__ void init_k(int* count, int* needed, float* scal, int Nn)
{
    int i = blockIdx.x * 256 + threadIdx.x;
    if (i < Nn) { count[i] = 0; needed[i] = 0; }
    if (i < 8) scal[i] = 0.f;
}

__global__ void mark_k(const int* __restrict__ nidx, int* __restrict__ needed, int B)
{
    int b = blockIdx.x * 256 + threadIdx.x;
    if (b < B) needed[nidx[b]] = 1;
}

// scal[0] = sum(edge_weight); scal[1+h] = sum_c lin_edge_w[h,c]*att_edge[h,c]
__global__ void prep_k(const float* __restrict__ ew, int E,
                       const float* __restrict__ lew, const float* __restrict__ ae,
                       float* __restrict__ scal)
{
    float s = 0.f;
    for (int i = blockIdx.x * 256 + threadIdx.x; i < E; i += gridDim.x * 256) s += ew[i];
    __shared__ float red[256];
    red[threadIdx.x] = s;
    __syncthreads();
    for (int off = 128; off; off >>= 1) {
        if (threadIdx.x < off) red[threadIdx.x] += red[threadIdx.x + off];
        __syncthreads();
    }
    if (threadIdx.x == 0) atomicAdd(&scal[0], red[0]);
    if (blockIdx.x == 0) {
        int w = threadIdx.x / 64, lane = threadIdx.x % 64;
        float c = 0.f;
        for (int cc = lane; cc < 256; cc += 64) c += lew[w * 256 + cc] * ae[w * 256 + cc];
        for (int off = 32; off; off >>= 1) c += __shfl_down(c, off);
        if (lane == 0) scal[1 + w] = c;
    }
}

__global__ void att_dots_k(const float* __restrict__ xp, const float* __restrict__ asrc_w,
                           const float* __restrict__ adst_w, float* __restrict__ a_src,
                           float* __restrict__ a_dst)
{
    int node = blockIdx.x;
    int w = threadIdx.x / 64, lane = threadIdx.x % 64;
    const float* row = xp + (size_t)node * 1024 + w * 256;
    float s1 = 0.f, s2 = 0.f;
#pragma unroll
    for (int c = lane; c < 256; c += 64) {
        float v = row[c];
        s1 += v * asrc_w[w * 256 + c];
        s2 += v * adst_w[w * 256 + c];
    }
    for (int off = 32; off; off >>= 1) { s1 += __shfl_down(s1, off); s2 += __shfl_down(s2, off); }
    if (lane == 0) { a_src[node * 4 + w] = s1; a_dst[node * 4 + w] = s2; }
}

__global__ void count_k(const int* __restrict__ ei, const int* __restrict__ needed,
                        int* __restrict__ count, int E, int Nn)
{
    int e = blockIdx.x * 256 + threadIdx.x;
    if (e >= E + Nn) return;
    int d = (e < E) ? ei[E + e] : e - E;
    if (needed[d]) atomicAdd(&count[d], 1);
}

__global__ __launch_bounds__(1024) void scan_k(const int* __restrict__ count, int* __restrict__ offs, int Nn)
{
    __shared__ int buf[1024];
    __shared__ int carry;
    int t = threadIdx.x;
    if (t == 0) carry = 0;
    __syncthreads();
    for (int base = 0; base < Nn; base += 1024) {
        int v = (base + t < Nn) ? count[base + t] : 0;
        buf[t] = v;
        __syncthreads();
        for (int off = 1; off < 1024; off <<= 1) {
            int add = (t >= off) ? buf[t - off] : 0;
            __syncthreads();
            buf[t] += add;
            __syncthreads();
        }
        if (base + t < Nn) offs[base + t] = carry + buf[t] - v;
        __syncthreads();
        if (t == 0) carry += buf[1023];
        __syncthreads();
    }
}

__global__ void fill_k(const int* __restrict__ ei, const int* __restrict__ needed,
                       int* __restrict__ offs, int* __restrict__ eid, int E, int Nn)
{
    int e = blockIdx.x * 256 + threadIdx.x;
    if (e >= E + Nn) return;
    int d = (e < E) ? ei[E + e] : e - E;
    if (!needed[d]) return;
    int p = atomicAdd(&offs[d], 1);
    eid[p] = e;
}

// fused GAT softmax + aggregation; epilogue emits elu(out+gat_bias) pre-split to bf16 hi/lo
#define CH 256
__global__ __launch_bounds__(256)
void gat_agg_k(const int* __restrict__ ei, const float* __restrict__ ew,
               const float* __restrict__ scal, const float* __restrict__ a_src,
               const float* __restrict__ a_dst, const int* __restrict__ needed,
               const int* __restrict__ count, const int* __restrict__ offs_end,
               const int* __restrict__ eid, const float* __restrict__ xp,
               const float* __restrict__ gat_bias,
               unsigned short* __restrict__ aggh, unsigned short* __restrict__ aggl,
               int E, int Nn)
{
    int d = blockIdx.x;
    if (!needed[d]) return;
    int c = count[d];
    int start = offs_end[d] - c;
    int tid = threadIdx.x;
    __shared__ int   srcs[CH];
    __shared__ float al[CH * 4];
    __shared__ float mrun[4], drun[4], scale[4];
    if (tid < 4) { mrun[tid] = -1e30f; drun[tid] = 0.f; }
    float4 acc = make_float4(0.f, 0.f, 0.f, 0.f);
    const int h = tid >> 6;
    const int x = tid * 4;
    const float adst0 = a_dst[d * 4 + 0], adst1 = a_dst[d * 4 + 1],
                adst2 = a_dst[d * 4 + 2], adst3 = a_dst[d * 4 + 3];

    for (int cb = 0; cb < c; cb += CH) {
        int cc = min(CH, c - cb);
        __syncthreads();
        for (int t = tid; t < cc * 4; t += 256) {
            int j = t >> 2, hh = t & 3;
            int e = eid[start + cb + j];
            int s; float ea;
            if (e < E) { s = ei[e]; ea = ew[e]; }
            else       { s = e - E; ea = scal[0] / (float)E; }
            float ad = hh == 0 ? adst0 : hh == 1 ? adst1 : hh == 2 ? adst2 : adst3;
            float a = a_src[s * 4 + hh] + ad + ea * scal[1 + hh];
            a = a > 0.f ? a : 0.2f * a;
            al[j * 4 + hh] = a;
            if (hh == 0) srcs[j] = s;
        }
        __syncthreads();
        if (tid < 4) {
            float m = -1e30f;
            for (int j = 0; j < cc; j++) m = fmaxf(m, al[j * 4 + tid]);
            float nm = fmaxf(mrun[tid], m);
            float sc = expf(mrun[tid] - nm);
            scale[tid] = sc;
            drun[tid] *= sc;
            mrun[tid] = nm;
        }
        __syncthreads();
        for (int t = tid; t < cc * 4; t += 256) {
            int j = t >> 2, hh = t & 3;
            al[j * 4 + hh] = expf(al[j * 4 + hh] - mrun[hh]);
        }
        __syncthreads();
        if (tid < 4) {
            float s = 0.f;
            for (int j = 0; j < cc; j++) s += al[j * 4 + tid];
            drun[tid] += s;
        }
        float sc = scale[h];
        acc.x *= sc; acc.y *= sc; acc.z *= sc; acc.w *= sc;
        for (int j = 0; j < cc; j++) {
            float w = al[j * 4 + h];
            const float4 v = *(const float4*)(xp + (size_t)srcs[j] * 1024 + x);
            acc.x = fmaf(w, v.x, acc.x);
            acc.y = fmaf(w, v.y, acc.y);
            acc.z = fmaf(w, v.z, acc.z);
            acc.w = fmaf(w, v.w, acc.w);
        }
    }
    __syncthreads();
    float dn = drun[h];
    float4 gb = *(const float4*)(gat_bias + x);
    float t0 = acc.x / dn + gb.x, t1 = acc.y / dn + gb.y,
          t2 = acc.z / dn + gb.z, t3 = acc.w / dn + gb.w;
    t0 = t0 > 0.f ? t0 : expf(t0) - 1.f;
    t1 = t1 > 0.f ? t1 : expf(t1) - 1.f;
    t2 = t2 > 0.f ? t2 : expf(t2) - 1.f;
    t3 = t3 > 0.f ? t3 : expf(t3) - 1.f;
    ushort4 hh, ll;
    split2(t0, hh.x, ll.x);
    split2(t1, hh.y, ll.y);
    split2(t2, hh.z, ll.z);
    split2(t3, hh.w, ll.w);
    *(ushort4*)(aggh + (size_t)d * 1024 + x) = hh;
    *(ushort4*)(aggl + (size_t)d * 1024 + x) = ll;
}

// h_heur = gelu(heur[B,6] @ heur_w[256,6]^T + heur_b)
__global__ void heur_k(const float* __restrict__ heur, const float* __restrict__ hw,
                       const float* __restrict__ hb, float* __restrict__ out)
{
    int b = blockIdx.x, n = threadIdx.x;
    float s = hb[n];
#pragma unroll
    for (int j = 0; j < 6; j++) s += heur[b * 6 + j] * hw[n * 6 + j];
    out[(size_t)b * 256 + n] = gelu_f(s);
}

__global__ void fuse_k(const float* __restrict__ h_heur, const float* __restrict__ g,
                       const float* __restrict__ h_sem, const float* __restrict__ h_struct,
                       const float* __restrict__ hwp, float* __restrict__ h_fused, int n)
{
    int i = blockIdx.x * 256 + threadIdx.x;
    if (i >= n) return;
    float hw = hwp[0];
    float gg = g[i];
    float hl = gg * h_sem[i] + (1.f - gg) * h_struct[i];
    h_fused[i] = hw * h_heur[i] + (1.f - hw) * hl;
}

__global__ void score_k(const float* __restrict__ s1, const float* __restrict__ sw2,
                        const float* __restrict__ sb2, float* __restrict__ out, int B)
{
    int b = blockIdx.x * 4 + threadIdx.x / 64;
    int lane = threadIdx.x % 64;
    if (b >= B) return;
    float4 v = *(const float4*)(s1 + (size_t)b * 256 + lane * 4);
    float4 w = *(const float4*)(sw2 + lane * 4);
    float s = v.x * w.x + v.y * w.y + v.z * w.z + v.w * w.w;
    for (int off = 32; off; off >>= 1) s += __shfl_down(s, off);
    if (lane == 0) out[b] = s + sb2[0];
}

// ---------------- launch ----------------

extern "C" void kernel_launch(void* const* d_in, const int* in_sizes, int n_in,
                              void* d_out, int out_size, void* d_ws, size_t ws_size,
                              hipStream_t stream)
{
    const float* sem      = (const float*)d_in[0];
    const float* gx       = (const float*)d_in[1];
    const int*   ei       = (const int*)d_in[2];
    const float* ew       = (const float*)d_in[3];
    const float* heur     = (const float*)d_in[4];
    const int*   nidx     = (const int*)d_in[5];
    const float* sem_w1   = (const float*)d_in[6];
    const float* sem_b1   = (const float*)d_in[7];
    const float* sem_w2   = (const float*)d_in[8];
    const float* sem_b2   = (const float*)d_in[9];
    const float* lin_w    = (const float*)d_in[10];
    const float* lin_edge = (const float*)d_in[11];
    const float* att_src  = (const float*)d_in[12];
    const float* att_dst  = (const float*)d_in[13];
    const float* att_edge = (const float*)d_in[14];
    const float* gat_bias = (const float*)d_in[15];
    const float* struct_w = (const float*)d_in[16];
    const float* struct_b = (const float*)d_in[17];
    const float* gate_w   = (const float*)d_in[18];
    const float* gate_b   = (const float*)d_in[19];
    const float* heur_w   = (const float*)d_in[20];
    const float* heur_b   = (const float*)d_in[21];
    const float* hwp      = (const float*)d_in[22];
    const float* sw1      = (const float*)d_in[23];
    const float* sb1      = (const float*)d_in[24];
    const float* sw2      = (const float*)d_in[25];
    const float* sb2      = (const float*)d_in[26];
    float* out = (float*)d_out;

    const int DIN = 768, HC = 1024, HID = 256;
    const int B  = in_sizes[0] / (2 * DIN);
    const int Nn = in_sizes[1] / DIN;
    const int E  = in_sizes[3];

    float* ws = (float*)d_ws;
    size_t off = 0;
    auto alloc = [&](size_t n) { float* p = ws + off; off += n; return p; };
    auto allocU = [&](size_t nelem) { return (unsigned short*)alloc((nelem + 1) / 2); };

    float* xp        = alloc((size_t)Nn * HC);           // x_proj f32 [N,1024]
    unsigned short* aggh = allocU((size_t)Nn * HC);      // elu(agg+bias) bf16 hi
    unsigned short* aggl = allocU((size_t)Nn * HC);      //                 ... lo
    float* h_sem    = alloc((size_t)B * HID);
    float* h_struct = alloc((size_t)B * HID);
    float* h_heur   = alloc((size_t)B * HID);
    float* gbuf     = alloc((size_t)B * HID);
    float* h_fused  = alloc((size_t)B * HID);
    float* s1       = alloc((size_t)B * HID);
    float* a_src    = alloc((size_t)Nn * 4);
    float* a_dst    = alloc((size_t)Nn * 4);
    int* countb     = (int*)alloc((size_t)Nn);
    int* offsb      = (int*)alloc((size_t)Nn);
    int* neededb    = (int*)alloc((size_t)Nn);
    int* eidb       = (int*)alloc((size_t)(E + Nn));
    float* scal     = alloc(8);
    // weight bf16 hi/lo
    unsigned short* linw_h = allocU((size_t)HC * DIN);
    unsigned short* linw_l = allocU((size_t)HC * DIN);
    unsigned short* sw1w_h = allocU((size_t)HID * 2 * DIN);
    unsigned short* sw1w_l = allocU((size_t)HID * 2 * DIN);
    unsigned short* sw2w_h = allocU((size_t)HID * HID);
    unsigned short* sw2w_l = allocU((size_t)HID * HID);
    unsigned short* stw_h  = allocU((size_t)HID * HC);
    unsigned short* stw_l  = allocU((size_t)HID * HC);
    unsigned short* gaw_h  = allocU((size_t)HID * 512);
    unsigned short* gaw_l  = allocU((size_t)HID * 512);
    unsigned short* scw_h  = allocU((size_t)HID * HID);
    unsigned short* scw_l  = allocU((size_t)HID * HID);
    // shared A-conversion buffer (sequential reuse): max = gx (Nn*DIN elems hi+lo)
    size_t abuf_elems = (size_t)Nn * DIN;
    unsigned short* abuf = allocU(abuf_elems * 2);
    (void)ws_size; (void)n_in; (void)out_size;

    // --- setup: CSR + scalars ---
    init_k<<<(Nn + 255) / 256, 256, 0, stream>>>(countb, neededb, scal, Nn);
    mark_k<<<(B + 255) / 256, 256, 0, stream>>>(nidx, neededb, B);
    prep_k<<<256, 256, 0, stream>>>(ew, E, lin_edge, att_edge, scal);
    int tot = E + Nn;
    count_k<<<(tot + 255) / 256, 256, 0, stream>>>(ei, neededb, countb, E, Nn);
    scan_k<<<1, 1024, 0, stream>>>(countb, offsb, Nn);
    fill_k<<<(tot + 255) / 256, 256, 0, stream>>>(ei, neededb, offsb, eidb, E, Nn);

    // --- weight conversions ---
    auto cvt = [&](const float* src, unsigned short* h, unsigned short* l, size_t n) {
        cvt_k<<<(int)((n / 4 + 255) / 256), 256, 0, stream>>>(src, h, l, (int)(n / 4));
    };
    cvt(lin_w, linw_h, linw_l, (size_t)HC * DIN);
    cvt(sem_w1, sw1w_h, sw1w_l, (size_t)HID * 2 * DIN);
    cvt(sem_w2, sw2w_h, sw2w_l, (size_t)HID * HID);
    cvt(struct_w, stw_h, stw_l, (size_t)HID * HC);
    cvt(gate_w, gaw_h, gaw_l, (size_t)HID * 512);
    cvt(sw1, scw_h, scw_l, (size_t)HID * HID);

    // --- semantic MLP (MFMA) ---
    cvt(sem, abuf, abuf + (size_t)B * 2 * DIN, (size_t)B * 2 * DIN);
    dim3 gs(HID / 64, B / 64);
    mgemm_k<2, 2, 2, 2, 1, 0><<<gs, 256, 0, stream>>>(abuf, abuf + (size_t)B * 2 * DIN, nullptr,
                                                      sw1w_h, sw1w_l, sem_b1, s1, B, HID, 2 * DIN);
    cvt(s1, abuf, abuf + (size_t)B * HID, (size_t)B * HID);
    mgemm_k<2, 2, 2, 2, 0, 0><<<gs, 256, 0, stream>>>(abuf, abuf + (size_t)B * HID, nullptr,
                                                      sw2w_h, sw2w_l, sem_b2, h_sem, B, HID, HID);

    // --- graph branch ---
    cvt(gx, abuf, abuf + (size_t)Nn * DIN, (size_t)Nn * DIN);
    dim3 gxg(HC / 128, (Nn + 127) / 128);
    mgemm_k<4, 4, 2, 2, 0, 0><<<gxg, 256, 0, stream>>>(abuf, abuf + (size_t)Nn * DIN, nullptr,
                                                       linw_h, linw_l, nullptr, xp, Nn, HC, DIN);
    att_dots_k<<<Nn, 256, 0, stream>>>(xp, att_src, att_dst, a_src, a_dst);
    gat_agg_k<<<Nn, 256, 0, stream>>>(ei, ew, scal, a_src, a_dst, neededb, countb, offsb, eidb,
                                      xp, gat_bias, aggh, aggl, E, Nn);

    // h_struct = gelu( gathered-elu-agg @ struct_w^T + struct_b )
    mgemm_k<2, 2, 2, 2, 1, 1><<<gs, 256, 0, stream>>>(aggh, aggl, nidx,
                                                      stw_h, stw_l, struct_b, h_struct, B, HID, HC);

    // --- fusion head ---
    heur_k<<<B, 256, 0, stream>>>(heur, heur_w, heur_b, h_heur);

    cvt_concat_k<<<(B * 128 + 255) / 256, 256, 0, stream>>>(h_sem, h_struct, abuf,
                                                            abuf + (size_t)B * 512, B);
    mgemm_k<2, 2, 2, 2, 2, 0><<<gs, 256, 0, stream>>>(abuf, abuf + (size_t)B * 512, nullptr,
                                                      gaw_h, gaw_l, gate_b, gbuf, B, HID, 512);

    fuse_k<<<(B * HID + 255) / 256, 256, 0, stream>>>(h_heur, gbuf, h_sem, h_struct, hwp, h_fused, B * HID);

    cvt(h_fused, abuf, abuf + (size_t)B * HID, (size_t)B * HID);
    mgemm_k<2, 2, 2, 2, 1, 0><<<gs, 256, 0, stream>>>(abuf, abuf + (size_t)B * HID, nullptr,
                                                      scw_h, scw_l, sb1, s1, B, HID, HID);

    score_k<<<B / 4, 256, 0, stream>>>(s1, sw2, sb2, out, B);
}

// Round 4
// 323.207 us; speedup vs baseline: 5.5906x; 1.5890x over previous
//
#include <hip/hip_runtime.h>
#include <math.h>

#define DEV __device__ __forceinline__

typedef __attribute__((ext_vector_type(8))) short bf16x8;
typedef __attribute__((ext_vector_type(4))) float f32x4;

DEV float gelu_f(float x) { return 0.5f * x * (1.f + erff(x * 0.70710678118654752440f)); }

DEV unsigned short f2bf(float f) {
    unsigned u = __float_as_uint(f);
    u += 0x7FFF + ((u >> 16) & 1);
    return (unsigned short)(u >> 16);
}
DEV float bf2f(unsigned short h) { return __uint_as_float(((unsigned)h) << 16); }
DEV void split2(float v, unsigned short& h, unsigned short& l) {
    h = f2bf(v);
    l = f2bf(v - bf2f(h));
}

// async global->LDS, 16B per lane; LDS dest = wave-uniform base + lane*16 (linear)
DEV void gload_lds16(const void* g, void* l) {
    __builtin_amdgcn_global_load_lds((const __attribute__((address_space(1))) void*)g,
                                     (__attribute__((address_space(3))) void*)l, 16, 0, 0);
}

// ---------------- split-bf16 MFMA GEMM, LDS-staged (m97 structure) ----------------
// C[M,N] = act(A[M,K] @ W[N,K]^T + bias); A,W as bf16 hi/lo pairs (row-major, K contig).
// BK=64. T2 XOR-swizzle: LDS row of 128B; 16B slot s at row r holds global slot s^(r&7).
// T1 XCD swizzle on 1-D grid. GATHER: A row m -> gidx[m]. EPI: 0 none, 1 GELU, 2 sigmoid.
template<int FM, int FN, int WR, int WC, int EPI, int GATHER>
__global__ __launch_bounds__(WR* WC * 64)
void mgemm_k(const unsigned short* __restrict__ Ah, const unsigned short* __restrict__ Al,
             const int* __restrict__ gidx,
             const unsigned short* __restrict__ Wh, const unsigned short* __restrict__ Wl,
             const float* __restrict__ bias, float* __restrict__ C,
             int M, int N, int K, int nbx)
{
    constexpr int BM = WR * FM * 16, BN = WC * FN * 16;
    constexpr int NW = WR * WC;
    __shared__ alignas(16) unsigned short sAh[BM * 64], sAl[BM * 64];
    __shared__ alignas(16) unsigned short sWh[BN * 64], sWl[BN * 64];

    const int tid = threadIdx.x;
    const int lane = tid & 63;
    const int wid = tid >> 6;
    const int wr = wid / WC, wc = wid % WC;

    // XCD-aware block swizzle (bijective since nwg % 8 == 0 for all our launches)
    const int nwg = gridDim.x;
    int bid = blockIdx.x;
    int swz = ((nwg & 7) == 0) ? (bid & 7) * (nwg >> 3) + (bid >> 3) : bid;
    const int bx = swz % nbx, by = swz / nbx;
    const int row0 = by * BM;
    const int col0 = bx * BN;

    f32x4 acc[FM][FN];
#pragma unroll
    for (int i = 0; i < FM; i++)
#pragma unroll
        for (int j = 0; j < FN; j++) acc[i][j] = (f32x4){0.f, 0.f, 0.f, 0.f};

    const int srow = lane >> 3;   // row within an 8-row staging call
    const int sslot = lane & 7;   // 16B slot within the 128B row

    for (int k0 = 0; k0 < K; k0 += 64) {
        // --- stage A tiles (hi+lo), pre-swizzled global source ---
#pragma unroll
        for (int c = 0; c < BM / 8 / NW; c++) {
            int call = c * NW + wid;
            int r = call * 8 + srow;
            int gr = row0 + r;
            gr = gr < M ? gr : M - 1;
            if (GATHER) gr = gidx[gr];
            int b = (sslot ^ (r & 7)) << 4;
            gload_lds16((const char*)(Ah + (size_t)gr * K + k0) + b, (char*)sAh + call * 1024);
            gload_lds16((const char*)(Al + (size_t)gr * K + k0) + b, (char*)sAl + call * 1024);
        }
        // --- stage W tiles ---
#pragma unroll
        for (int c = 0; c < BN / 8 / NW; c++) {
            int call = c * NW + wid;
            int r = call * 8 + srow;
            int gr = col0 + r;
            int b = (sslot ^ (r & 7)) << 4;
            gload_lds16((const char*)(Wh + (size_t)gr * K + k0) + b, (char*)sWh + call * 1024);
            gload_lds16((const char*)(Wl + (size_t)gr * K + k0) + b, (char*)sWl + call * 1024);
        }
        __syncthreads();   // drains vmcnt (compiler emits waitcnt before s_barrier)

        const int fr = lane & 15, kq = lane >> 4;
#pragma unroll
        for (int ks = 0; ks < 2; ks++) {
            bf16x8 ah[FM], al[FM], bh[FN], bl[FN];
#pragma unroll
            for (int i = 0; i < FM; i++) {
                int r = wr * FM * 16 + i * 16 + fr;
                int b = ((ks * 4 + kq) ^ (r & 7)) << 4;
                ah[i] = *(const bf16x8*)((const char*)sAh + r * 128 + b);
                al[i] = *(const bf16x8*)((const char*)sAl + r * 128 + b);
            }
#pragma unroll
            for (int j = 0; j < FN; j++) {
                int r = wc * FN * 16 + j * 16 + fr;
                int b = ((ks * 4 + kq) ^ (r & 7)) << 4;
                bh[j] = *(const bf16x8*)((const char*)sWh + r * 128 + b);
                bl[j] = *(const bf16x8*)((const char*)sWl + r * 128 + b);
            }
#pragma unroll
            for (int i = 0; i < FM; i++)
#pragma unroll
                for (int j = 0; j < FN; j++) {
                    acc[i][j] = __builtin_amdgcn_mfma_f32_16x16x32_bf16(ah[i], bh[j], acc[i][j], 0, 0, 0);
                    acc[i][j] = __builtin_amdgcn_mfma_f32_16x16x32_bf16(al[i], bh[j], acc[i][j], 0, 0, 0);
                    acc[i][j] = __builtin_amdgcn_mfma_f32_16x16x32_bf16(ah[i], bl[j], acc[i][j], 0, 0, 0);
                }
        }
        __syncthreads();
    }

    const int fr = lane & 15;
    const int r0 = (lane >> 4) * 4;   // C/D: col = lane&15, row = (lane>>4)*4 + reg
#pragma unroll
    for (int i = 0; i < FM; i++) {
#pragma unroll
        for (int jj = 0; jj < 4; jj++) {
            int gr = row0 + wr * FM * 16 + i * 16 + r0 + jj;
            if (gr >= M) continue;
#pragma unroll
            for (int j = 0; j < FN; j++) {
                int gc = col0 + wc * FN * 16 + j * 16 + fr;
                float v = acc[i][j][jj] + (bias ? bias[gc] : 0.f);
                if (EPI == 1) v = gelu_f(v);
                else if (EPI == 2) v = 1.f / (1.f + expf(-v));
                C[(size_t)gr * N + gc] = v;
            }
        }
    }
}

// ---------------- conversion kernels ----------------

__global__ void cvt_k(const float* __restrict__ src, unsigned short* __restrict__ hi,
                      unsigned short* __restrict__ lo, int n4)
{
    int i = blockIdx.x * 256 + threadIdx.x;
    if (i >= n4) return;
    float4 v = ((const float4*)src)[i];
    ushort4 h, l;
    split2(v.x, h.x, l.x);
    split2(v.y, h.y, l.y);
    split2(v.z, h.z, l.z);
    split2(v.w, h.w, l.w);
    ((ushort4*)hi)[i] = h;
    ((ushort4*)lo)[i] = l;
}

// concat(h_sem, h_struct) [B,512] -> hi/lo
__global__ void cvt_concat_k(const float* __restrict__ a, const float* __restrict__ b,
                             unsigned short* __restrict__ hi, unsigned short* __restrict__ lo, int B)
{
    int i = blockIdx.x * 256 + threadIdx.x;
    if (i >= B * 128) return;  // groups of 4 cols
    int row = i >> 7, g = i & 127;
    const float* src = (g < 64) ? a + (size_t)row * 256 + g * 4 : b + (size_t)row * 256 + (g - 64) * 4;
    float4 v = *(const float4*)src;
    ushort4 h, l;
    split2(v.x, h.x, l.x);
    split2(v.y, h.y, l.y);
    split2(v.z, h.z, l.z);
    split2(v.w, h.w, l.w);
    ((ushort4*)hi)[i] = h;
    ((ushort4*)lo)[i] = l;
}

// ---------------- setup / graph kernels ----------------

__global__ void init_k(int* count, int* needed, float* scal, int Nn)
{
    int i = blockIdx.x * 256 + threadIdx.x;
    if (i < Nn) { count[i] = 0; needed[i] = 0; }
    if (i < 8) scal[i] = 0.f;
}

__global__ void mark_k(const int* __restrict__ nidx, int* __restrict__ needed, int B)
{
    int b = blockIdx.x * 256 + threadIdx.x;
    if (b < B) needed[nidx[b]] = 1;
}

// scal[0] = sum(edge_weight); scal[1+h] = sum_c lin_edge_w[h,c]*att_edge[h,c]
__global__ void prep_k(const float* __restrict__ ew, int E,
                       const float* __restrict__ lew, const float* __restrict__ ae,
                       float* __restrict__ scal)
{
    float s = 0.f;
    for (int i = blockIdx.x * 256 + threadIdx.x; i < E; i += gridDim.x * 256) s += ew[i];
    __shared__ float red[256];
    red[threadIdx.x] = s;
    __syncthreads();
    for (int off = 128; off; off >>= 1) {
        if (threadIdx.x < off) red[threadIdx.x] += red[threadIdx.x + off];
        __syncthreads();
    }
    if (threadIdx.x == 0) atomicAdd(&scal[0], red[0]);
    if (blockIdx.x == 0) {
        int w = threadIdx.x / 64, lane = threadIdx.x % 64;
        float c = 0.f;
        for (int cc = lane; cc < 256; cc += 64) c += lew[w * 256 + cc] * ae[w * 256 + cc];
        for (int off = 32; off; off >>= 1) c += __shfl_down(c, off);
        if (lane == 0) scal[1 + w] = c;
    }
}

__global__ void att_dots_k(const float* __restrict__ xp, const float* __restrict__ asrc_w,
                           const float* __restrict__ adst_w, float* __restrict__ a_src,
                           float* __restrict__ a_dst)
{
    int node = blockIdx.x;
    int w = threadIdx.x / 64, lane = threadIdx.x % 64;
    const float* row = xp + (size_t)node * 1024 + w * 256;
    float s1 = 0.f, s2 = 0.f;
#pragma unroll
    for (int c = lane; c < 256; c += 64) {
        float v = row[c];
        s1 += v * asrc_w[w * 256 + c];
        s2 += v * adst_w[w * 256 + c];
    }
    for (int off = 32; off; off >>= 1) { s1 += __shfl_down(s1, off); s2 += __shfl_down(s2, off); }
    if (lane == 0) { a_src[node * 4 + w] = s1; a_dst[node * 4 + w] = s2; }
}

__global__ void count_k(const int* __restrict__ ei, const int* __restrict__ needed,
                        int* __restrict__ count, int E, int Nn)
{
    int e = blockIdx.x * 256 + threadIdx.x;
    if (e >= E + Nn) return;
    int d = (e < E) ? ei[E + e] : e - E;
    if (needed[d]) atomicAdd(&count[d], 1);
}

__global__ __launch_bounds__(1024) void scan_k(const int* __restrict__ count, int* __restrict__ offs, int Nn)
{
    __shared__ int buf[1024];
    __shared__ int carry;
    int t = threadIdx.x;
    if (t == 0) carry = 0;
    __syncthreads();
    for (int base = 0; base < Nn; base += 1024) {
        int v = (base + t < Nn) ? count[base + t] : 0;
        buf[t] = v;
        __syncthreads();
        for (int off = 1; off < 1024; off <<= 1) {
            int add = (t >= off) ? buf[t - off] : 0;
            __syncthreads();
            buf[t] += add;
            __syncthreads();
        }
        if (base + t < Nn) offs[base + t] = carry + buf[t] - v;
        __syncthreads();
        if (t == 0) carry += buf[1023];
        __syncthreads();
    }
}

__global__ void fill_k(const int* __restrict__ ei, const int* __restrict__ needed,
                       int* __restrict__ offs, int* __restrict__ eid, int E, int Nn)
{
    int e = blockIdx.x * 256 + threadIdx.x;
    if (e >= E + Nn) return;
    int d = (e < E) ? ei[E + e] : e - E;
    if (!needed[d]) return;
    int p = atomicAdd(&offs[d], 1);
    eid[p] = e;
}

// fused GAT softmax + aggregation; epilogue emits elu(out+gat_bias) pre-split to bf16 hi/lo
#define CH 256
__global__ __launch_bounds__(256)
void gat_agg_k(const int* __restrict__ ei, const float* __restrict__ ew,
               const float* __restrict__ scal, const float* __restrict__ a_src,
               const float* __restrict__ a_dst, const int* __restrict__ needed,
               const int* __restrict__ count, const int* __restrict__ offs_end,
               const int* __restrict__ eid, const float* __restrict__ xp,
               const float* __restrict__ gat_bias,
               unsigned short* __restrict__ aggh, unsigned short* __restrict__ aggl,
               int E, int Nn)
{
    int d = blockIdx.x;
    if (!needed[d]) return;
    int c = count[d];
    int start = offs_end[d] - c;
    int tid = threadIdx.x;
    __shared__ int   srcs[CH];
    __shared__ float al[CH * 4];
    __shared__ float mrun[4], drun[4], scale[4];
    if (tid < 4) { mrun[tid] = -1e30f; drun[tid] = 0.f; }
    float4 acc = make_float4(0.f, 0.f, 0.f, 0.f);
    const int h = tid >> 6;
    const int x = tid * 4;
    const float adst0 = a_dst[d * 4 + 0], adst1 = a_dst[d * 4 + 1],
                adst2 = a_dst[d * 4 + 2], adst3 = a_dst[d * 4 + 3];

    for (int cb = 0; cb < c; cb += CH) {
        int cc = min(CH, c - cb);
        __syncthreads();
        for (int t = tid; t < cc * 4; t += 256) {
            int j = t >> 2, hh = t & 3;
            int e = eid[start + cb + j];
            int s; float ea;
            if (e < E) { s = ei[e]; ea = ew[e]; }
            else       { s = e - E; ea = scal[0] / (float)E; }
            float ad = hh == 0 ? adst0 : hh == 1 ? adst1 : hh == 2 ? adst2 : adst3;
            float a = a_src[s * 4 + hh] + ad + ea * scal[1 + hh];
            a = a > 0.f ? a : 0.2f * a;
            al[j * 4 + hh] = a;
            if (hh == 0) srcs[j] = s;
        }
        __syncthreads();
        if (tid < 4) {
            float m = -1e30f;
            for (int j = 0; j < cc; j++) m = fmaxf(m, al[j * 4 + tid]);
            float nm = fmaxf(mrun[tid], m);
            float sc = expf(mrun[tid] - nm);
            scale[tid] = sc;
            drun[tid] *= sc;
            mrun[tid] = nm;
        }
        __syncthreads();
        for (int t = tid; t < cc * 4; t += 256) {
            int j = t >> 2, hh = t & 3;
            al[j * 4 + hh] = expf(al[j * 4 + hh] - mrun[hh]);
        }
        __syncthreads();
        if (tid < 4) {
            float s = 0.f;
            for (int j = 0; j < cc; j++) s += al[j * 4 + tid];
            drun[tid] += s;
        }
        float sc = scale[h];
        acc.x *= sc; acc.y *= sc; acc.z *= sc; acc.w *= sc;
        for (int j = 0; j < cc; j++) {
            float w = al[j * 4 + h];
            const float4 v = *(const float4*)(xp + (size_t)srcs[j] * 1024 + x);
            acc.x = fmaf(w, v.x, acc.x);
            acc.y = fmaf(w, v.y, acc.y);
            acc.z = fmaf(w, v.z, acc.z);
            acc.w = fmaf(w, v.w, acc.w);
        }
    }
    __syncthreads();
    float dn = drun[h];
    float4 gb = *(const float4*)(gat_bias + x);
    float t0 = acc.x / dn + gb.x, t1 = acc.y / dn + gb.y,
          t2 = acc.z / dn + gb.z, t3 = acc.w / dn + gb.w;
    t0 = t0 > 0.f ? t0 : expf(t0) - 1.f;
    t1 = t1 > 0.f ? t1 : expf(t1) - 1.f;
    t2 = t2 > 0.f ? t2 : expf(t2) - 1.f;
    t3 = t3 > 0.f ? t3 : expf(t3) - 1.f;
    ushort4 hh, ll;
    split2(t0, hh.x, ll.x);
    split2(t1, hh.y, ll.y);
    split2(t2, hh.z, ll.z);
    split2(t3, hh.w, ll.w);
    *(ushort4*)(aggh + (size_t)d * 1024 + x) = hh;
    *(ushort4*)(aggl + (size_t)d * 1024 + x) = ll;
}

// h_heur = gelu(heur[B,6] @ heur_w[256,6]^T + heur_b)
__global__ void heur_k(const float* __restrict__ heur, const float* __restrict__ hw,
                       const float* __restrict__ hb, float* __restrict__ out)
{
    int b = blockIdx.x, n = threadIdx.x;
    float s = hb[n];
#pragma unroll
    for (int j = 0; j < 6; j++) s += heur[b * 6 + j] * hw[n * 6 + j];
    out[(size_t)b * 256 + n] = gelu_f(s);
}

__global__ void fuse_k(const float* __restrict__ h_heur, const float* __restrict__ g,
                       const float* __restrict__ h_sem, const float* __restrict__ h_struct,
                       const float* __restrict__ hwp, float* __restrict__ h_fused, int n)
{
    int i = blockIdx.x * 256 + threadIdx.x;
    if (i >= n) return;
    float hw = hwp[0];
    float gg = g[i];
    float hl = gg * h_sem[i] + (1.f - gg) * h_struct[i];
    h_fused[i] = hw * h_heur[i] + (1.f - hw) * hl;
}

__global__ void score_k(const float* __restrict__ s1, const float* __restrict__ sw2,
                        const float* __restrict__ sb2, float* __restrict__ out, int B)
{
    int b = blockIdx.x * 4 + threadIdx.x / 64;
    int lane = threadIdx.x % 64;
    if (b >= B) return;
    float4 v = *(const float4*)(s1 + (size_t)b * 256 + lane * 4);
    float4 w = *(const float4*)(sw2 + lane * 4);
    float s = v.x * w.x + v.y * w.y + v.z * w.z + v.w * w.w;
    for (int off = 32; off; off >>= 1) s += __shfl_down(s, off);
    if (lane == 0) out[b] = s + sb2[0];
}

// ---------------- launch ----------------

extern "C" void kernel_launch(void* const* d_in, const int* in_sizes, int n_in,
                              void* d_out, int out_size, void* d_ws, size_t ws_size,
                              hipStream_t stream)
{
    const float* sem      = (const float*)d_in[0];
    const float* gx       = (const float*)d_in[1];
    const int*   ei       = (const int*)d_in[2];
    const float* ew       = (const float*)d_in[3];
    const float* heur     = (const float*)d_in[4];
    const int*   nidx     = (const int*)d_in[5];
    const float* sem_w1   = (const float*)d_in[6];
    const float* sem_b1   = (const float*)d_in[7];
    const float* sem_w2   = (const float*)d_in[8];
    const float* sem_b2   = (const float*)d_in[9];
    const float* lin_w    = (const float*)d_in[10];
    const float* lin_edge = (const float*)d_in[11];
    const float* att_src  = (const float*)d_in[12];
    const float* att_dst  = (const float*)d_in[13];
    const float* att_edge = (const float*)d_in[14];
    const float* gat_bias = (const float*)d_in[15];
    const float* struct_w = (const float*)d_in[16];
    const float* struct_b = (const float*)d_in[17];
    const float* gate_w   = (const float*)d_in[18];
    const float* gate_b   = (const float*)d_in[19];
    const float* heur_w   = (const float*)d_in[20];
    const float* heur_b   = (const float*)d_in[21];
    const float* hwp      = (const float*)d_in[22];
    const float* sw1      = (const float*)d_in[23];
    const float* sb1      = (const float*)d_in[24];
    const float* sw2      = (const float*)d_in[25];
    const float* sb2      = (const float*)d_in[26];
    float* out = (float*)d_out;

    const int DIN = 768, HC = 1024, HID = 256;
    const int B  = in_sizes[0] / (2 * DIN);
    const int Nn = in_sizes[1] / DIN;
    const int E  = in_sizes[3];

    float* ws = (float*)d_ws;
    size_t off = 0;
    auto alloc = [&](size_t n) { float* p = ws + off; off += n; return p; };
    auto allocU = [&](size_t nelem) { return (unsigned short*)alloc((nelem + 1) / 2); };

    float* xp        = alloc((size_t)Nn * HC);           // x_proj f32 [N,1024]
    unsigned short* aggh = allocU((size_t)Nn * HC);      // elu(agg+bias) bf16 hi
    unsigned short* aggl = allocU((size_t)Nn * HC);      //                 ... lo
    float* h_sem    = alloc((size_t)B * HID);
    float* h_struct = alloc((size_t)B * HID);
    float* h_heur   = alloc((size_t)B * HID);
    float* gbuf     = alloc((size_t)B * HID);
    float* h_fused  = alloc((size_t)B * HID);
    float* s1       = alloc((size_t)B * HID);
    float* a_src    = alloc((size_t)Nn * 4);
    float* a_dst    = alloc((size_t)Nn * 4);
    int* countb     = (int*)alloc((size_t)Nn);
    int* offsb      = (int*)alloc((size_t)Nn);
    int* neededb    = (int*)alloc((size_t)Nn);
    int* eidb       = (int*)alloc((size_t)(E + Nn));
    float* scal     = alloc(8);
    // weight bf16 hi/lo
    unsigned short* linw_h = allocU((size_t)HC * DIN);
    unsigned short* linw_l = allocU((size_t)HC * DIN);
    unsigned short* sw1w_h = allocU((size_t)HID * 2 * DIN);
    unsigned short* sw1w_l = allocU((size_t)HID * 2 * DIN);
    unsigned short* sw2w_h = allocU((size_t)HID * HID);
    unsigned short* sw2w_l = allocU((size_t)HID * HID);
    unsigned short* stw_h  = allocU((size_t)HID * HC);
    unsigned short* stw_l  = allocU((size_t)HID * HC);
    unsigned short* gaw_h  = allocU((size_t)HID * 512);
    unsigned short* gaw_l  = allocU((size_t)HID * 512);
    unsigned short* scw_h  = allocU((size_t)HID * HID);
    unsigned short* scw_l  = allocU((size_t)HID * HID);
    // shared A-conversion buffer (sequential reuse): max = gx (Nn*DIN elems hi+lo)
    size_t abuf_elems = (size_t)Nn * DIN;
    unsigned short* abuf = allocU(abuf_elems * 2);
    (void)ws_size; (void)n_in; (void)out_size;

    // --- setup: CSR + scalars ---
    init_k<<<(Nn + 255) / 256, 256, 0, stream>>>(countb, neededb, scal, Nn);
    mark_k<<<(B + 255) / 256, 256, 0, stream>>>(nidx, neededb, B);
    prep_k<<<256, 256, 0, stream>>>(ew, E, lin_edge, att_edge, scal);
    int tot = E + Nn;
    count_k<<<(tot + 255) / 256, 256, 0, stream>>>(ei, neededb, countb, E, Nn);
    scan_k<<<1, 1024, 0, stream>>>(countb, offsb, Nn);
    fill_k<<<(tot + 255) / 256, 256, 0, stream>>>(ei, neededb, offsb, eidb, E, Nn);

    // --- weight conversions ---
    auto cvt = [&](const float* src, unsigned short* h, unsigned short* l, size_t n) {
        cvt_k<<<(int)((n / 4 + 255) / 256), 256, 0, stream>>>(src, h, l, (int)(n / 4));
    };
    cvt(lin_w, linw_h, linw_l, (size_t)HC * DIN);
    cvt(sem_w1, sw1w_h, sw1w_l, (size_t)HID * 2 * DIN);
    cvt(sem_w2, sw2w_h, sw2w_l, (size_t)HID * HID);
    cvt(struct_w, stw_h, stw_l, (size_t)HID * HC);
    cvt(gate_w, gaw_h, gaw_l, (size_t)HID * 512);
    cvt(sw1, scw_h, scw_l, (size_t)HID * HID);

    const int nbs = HID / 64;           // 4  (64-col blocks for B x 256 GEMMs)
    const int nbys = B / 64;            // 64
    dim3 gs(nbs * nbys);                // 256 blocks, 1-D with internal swizzle

    // --- semantic MLP (MFMA) ---
    cvt(sem, abuf, abuf + (size_t)B * 2 * DIN, (size_t)B * 2 * DIN);
    mgemm_k<2, 2, 2, 2, 1, 0><<<gs, 256, 0, stream>>>(abuf, abuf + (size_t)B * 2 * DIN, nullptr,
                                                      sw1w_h, sw1w_l, sem_b1, s1, B, HID, 2 * DIN, nbs);
    cvt(s1, abuf, abuf + (size_t)B * HID, (size_t)B * HID);
    mgemm_k<2, 2, 2, 2, 0, 0><<<gs, 256, 0, stream>>>(abuf, abuf + (size_t)B * HID, nullptr,
                                                      sw2w_h, sw2w_l, sem_b2, h_sem, B, HID, HID, nbs);

    // --- graph branch ---
    cvt(gx, abuf, abuf + (size_t)Nn * DIN, (size_t)Nn * DIN);
    const int nbx_x = HC / 128;                 // 8
    const int nby_x = (Nn + 127) / 128;         // 79
    mgemm_k<4, 4, 2, 2, 0, 0><<<nbx_x * nby_x, 256, 0, stream>>>(abuf, abuf + (size_t)Nn * DIN, nullptr,
                                                                 linw_h, linw_l, nullptr, xp, Nn, HC, DIN, nbx_x);
    att_dots_k<<<Nn, 256, 0, stream>>>(xp, att_src, att_dst, a_src, a_dst);
    gat_agg_k<<<Nn, 256, 0, stream>>>(ei, ew, scal, a_src, a_dst, neededb, countb, offsb, eidb,
                                      xp, gat_bias, aggh, aggl, E, Nn);

    // h_struct = gelu( gathered-elu-agg @ struct_w^T + struct_b )
    mgemm_k<2, 2, 2, 2, 1, 1><<<gs, 256, 0, stream>>>(aggh, aggl, nidx,
                                                      stw_h, stw_l, struct_b, h_struct, B, HID, HC, nbs);

    // --- fusion head ---
    heur_k<<<B, 256, 0, stream>>>(heur, heur_w, heur_b, h_heur);

    cvt_concat_k<<<(B * 128 + 255) / 256, 256, 0, stream>>>(h_sem, h_struct, abuf,
                                                            abuf + (size_t)B * 512, B);
    mgemm_k<2, 2, 2, 2, 2, 0><<<gs, 256, 0, stream>>>(abuf, abuf + (size_t)B * 512, nullptr,
                                                      gaw_h, gaw_l, gate_b, gbuf, B, HID, 512, nbs);

    fuse_k<<<(B * HID + 255) / 256, 256, 0, stream>>>(h_heur, gbuf, h_sem, h_struct, hwp, h_fused, B * HID);

    cvt(h_fused, abuf, abuf + (size_t)B * HID, (size_t)B * HID);
    mgemm_k<2, 2, 2, 2, 1, 0><<<gs, 256, 0, stream>>>(abuf, abuf + (size_t)B * HID, nullptr,
                                                      scw_h, scw_l, sb1, s1, B, HID, HID, nbs);

    score_k<<<B / 4, 256, 0, stream>>>(s1, sw2, sb2, out, B);
}

// Round 5
// 259.416 us; speedup vs baseline: 6.9654x; 1.2459x over previous
//
#include <hip/hip_runtime.h>
#include <math.h>

#define DEV __device__ __forceinline__

typedef __attribute__((ext_vector_type(8))) short bf16x8;
typedef __attribute__((ext_vector_type(4))) float f32x4;

DEV float gelu_f(float x) { return 0.5f * x * (1.f + erff(x * 0.70710678118654752440f)); }

DEV unsigned short f2bf(float f) {
    unsigned u = __float_as_uint(f);
    u += 0x7FFF + ((u >> 16) & 1);
    return (unsigned short)(u >> 16);
}
DEV float bf2f(unsigned short h) { return __uint_as_float(((unsigned)h) << 16); }
DEV void split2(float v, unsigned short& h, unsigned short& l) {
    h = f2bf(v);
    l = f2bf(v - bf2f(h));
}

// async global->LDS, 16B per lane; LDS dest = wave-uniform base + lane*16 (linear)
DEV void gload_lds16(const void* g, void* l) {
    __builtin_amdgcn_global_load_lds((const __attribute__((address_space(1))) void*)g,
                                     (__attribute__((address_space(3))) void*)l, 16, 0, 0);
}

// ---------------- split-bf16 MFMA GEMM, LDS-staged ----------------
// C = act(A[M,K] @ W[N,K]^T + bias). BK=64, T2 XOR-swizzle (slot^row&7), T1 XCD swizzle.
// ASRC: 0 = A pre-split hi/lo (gload_lds); 1 = A f32, reg-stage + split + ds_write.
// GATHER: A row m -> gidx[m] (only with ASRC=0).
// EPI: 0 none, 1 exact GELU, 3 fused gate+heur+fusion (see below).
// OUT: 0 = f32 C; 1 = split-bf16 Ch/Cl only; 2 = f32 C AND split Ch/Cl at [row*ldsp+coff+col].
template<int FM, int FN, int WR, int WC, int EPI, int GATHER, int ASRC, int OUT>
__global__ __launch_bounds__(WR* WC * 64)
void mgemm_k(const unsigned short* __restrict__ Ah, const unsigned short* __restrict__ Al,
             const float* __restrict__ Af, const int* __restrict__ gidx,
             const unsigned short* __restrict__ Wh, const unsigned short* __restrict__ Wl,
             const float* __restrict__ bias,
             float* __restrict__ C, unsigned short* __restrict__ Ch, unsigned short* __restrict__ Cl,
             int ldsp, int coff,
             const float* __restrict__ fs_hsem, const float* __restrict__ fs_hstruct,
             const float* __restrict__ fs_heur, const float* __restrict__ fs_heurw,
             const float* __restrict__ fs_heurb, const float* __restrict__ fs_hw,
             int M, int N, int K, int nbx)
{
    constexpr int BM = WR * FM * 16, BN = WC * FN * 16;
    constexpr int NW = WR * WC;
    __shared__ alignas(16) unsigned short sAh[BM * 64], sAl[BM * 64];
    __shared__ alignas(16) unsigned short sWh[BN * 64], sWl[BN * 64];

    const int tid = threadIdx.x;
    const int lane = tid & 63;
    const int wid = tid >> 6;
    const int wr = wid / WC, wc = wid % WC;

    const int nwg = gridDim.x;
    int bid = blockIdx.x;
    int swz = ((nwg & 7) == 0) ? (bid & 7) * (nwg >> 3) + (bid >> 3) : bid;
    const int bx = swz % nbx, by = swz / nbx;
    const int row0 = by * BM;
    const int col0 = bx * BN;

    f32x4 acc[FM][FN];
#pragma unroll
    for (int i = 0; i < FM; i++)
#pragma unroll
        for (int j = 0; j < FN; j++) acc[i][j] = (f32x4){0.f, 0.f, 0.f, 0.f};

    const int srow = lane >> 3;   // row within an 8-row staging call
    const int sslot = lane & 7;   // 16B slot within the 128B row

    for (int k0 = 0; k0 < K; k0 += 64) {
        // --- stage A (hi+lo) ---
#pragma unroll
        for (int c = 0; c < BM / 8 / NW; c++) {
            int call = c * NW + wid;
            int r = call * 8 + srow;
            int gr = row0 + r;
            gr = gr < M ? gr : M - 1;
            if (ASRC == 0) {
                if (GATHER) gr = gidx[gr];
                int b = (sslot ^ (r & 7)) << 4;
                gload_lds16((const char*)(Ah + (size_t)gr * K + k0) + b, (char*)sAh + call * 1024);
                gload_lds16((const char*)(Al + (size_t)gr * K + k0) + b, (char*)sAl + call * 1024);
            } else {
                const float* sp = Af + (size_t)gr * K + k0 + sslot * 8;
                float vv[8];
                *(float4*)&vv[0] = *(const float4*)sp;
                *(float4*)&vv[4] = *(const float4*)(sp + 4);
                union { bf16x8 v; unsigned short u[8]; } ph, pl;
#pragma unroll
                for (int q = 0; q < 8; q++) split2(vv[q], ph.u[q], pl.u[q]);
                int b = (sslot ^ (r & 7)) << 4;
                *(bf16x8*)((char*)sAh + r * 128 + b) = ph.v;
                *(bf16x8*)((char*)sAl + r * 128 + b) = pl.v;
            }
        }
        // --- stage W ---
#pragma unroll
        for (int c = 0; c < BN / 8 / NW; c++) {
            int call = c * NW + wid;
            int r = call * 8 + srow;
            int gr = col0 + r;
            int b = (sslot ^ (r & 7)) << 4;
            gload_lds16((const char*)(Wh + (size_t)gr * K + k0) + b, (char*)sWh + call * 1024);
            gload_lds16((const char*)(Wl + (size_t)gr * K + k0) + b, (char*)sWl + call * 1024);
        }
        __syncthreads();

        const int fr = lane & 15, kq = lane >> 4;
#pragma unroll
        for (int ks = 0; ks < 2; ks++) {
            bf16x8 ah[FM], al[FM], bh[FN], bl[FN];
#pragma unroll
            for (int i = 0; i < FM; i++) {
                int r = wr * FM * 16 + i * 16 + fr;
                int b = ((ks * 4 + kq) ^ (r & 7)) << 4;
                ah[i] = *(const bf16x8*)((const char*)sAh + r * 128 + b);
                al[i] = *(const bf16x8*)((const char*)sAl + r * 128 + b);
            }
#pragma unroll
            for (int j = 0; j < FN; j++) {
                int r = wc * FN * 16 + j * 16 + fr;
                int b = ((ks * 4 + kq) ^ (r & 7)) << 4;
                bh[j] = *(const bf16x8*)((const char*)sWh + r * 128 + b);
                bl[j] = *(const bf16x8*)((const char*)sWl + r * 128 + b);
            }
#pragma unroll
            for (int i = 0; i < FM; i++)
#pragma unroll
                for (int j = 0; j < FN; j++) {
                    acc[i][j] = __builtin_amdgcn_mfma_f32_16x16x32_bf16(ah[i], bh[j], acc[i][j], 0, 0, 0);
                    acc[i][j] = __builtin_amdgcn_mfma_f32_16x16x32_bf16(al[i], bh[j], acc[i][j], 0, 0, 0);
                    acc[i][j] = __builtin_amdgcn_mfma_f32_16x16x32_bf16(ah[i], bl[j], acc[i][j], 0, 0, 0);
                }
        }
        __syncthreads();
    }

    const int fr = lane & 15;
    const int r0 = (lane >> 4) * 4;   // C/D: col = lane&15, row = (lane>>4)*4 + reg
#pragma unroll
    for (int i = 0; i < FM; i++) {
#pragma unroll
        for (int jj = 0; jj < 4; jj++) {
            int gr = row0 + wr * FM * 16 + i * 16 + r0 + jj;
            if (gr >= M) continue;
#pragma unroll
            for (int j = 0; j < FN; j++) {
                int gc = col0 + wc * FN * 16 + j * 16 + fr;
                float v = acc[i][j][jj] + (bias ? bias[gc] : 0.f);
                if (EPI == 1) v = gelu_f(v);
                else if (EPI == 3) {
                    float g = 1.f / (1.f + expf(-v));
                    float hh = fs_heurb[gc];
#pragma unroll
                    for (int q = 0; q < 6; q++) hh = fmaf(fs_heur[gr * 6 + q], fs_heurw[gc * 6 + q], hh);
                    hh = gelu_f(hh);
                    float hl = g * fs_hsem[(size_t)gr * 256 + gc] + (1.f - g) * fs_hstruct[(size_t)gr * 256 + gc];
                    float hwv = fs_hw[0];
                    v = hwv * hh + (1.f - hwv) * hl;
                }
                if (OUT == 0 || OUT == 2) C[(size_t)gr * N + gc] = v;
                if (OUT == 1 || OUT == 2) {
                    unsigned short h, l;
                    split2(v, h, l);
                    Ch[(size_t)gr * ldsp + coff + gc] = h;
                    Cl[(size_t)gr * ldsp + coff + gc] = l;
                }
            }
        }
    }
}

// ---------------- conversion kernels ----------------

__global__ void cvt_k(const float* __restrict__ src, unsigned short* __restrict__ hi,
                      unsigned short* __restrict__ lo, int n4)
{
    int i = blockIdx.x * 256 + threadIdx.x;
    if (i >= n4) return;
    float4 v = ((const float4*)src)[i];
    ushort4 h, l;
    split2(v.x, h.x, l.x);
    split2(v.y, h.y, l.y);
    split2(v.z, h.z, l.z);
    split2(v.w, h.w, l.w);
    ((ushort4*)hi)[i] = h;
    ((ushort4*)lo)[i] = l;
}

// 6 weight buffers -> hi/lo in one launch; e0..e5 are CUMULATIVE float4 counts
__global__ void wcvt_k(const float* s0, unsigned short* h0, unsigned short* l0, int e0,
                       const float* s1, unsigned short* h1, unsigned short* l1, int e1,
                       const float* s2, unsigned short* h2, unsigned short* l2, int e2,
                       const float* s3, unsigned short* h3, unsigned short* l3, int e3,
                       const float* s4, unsigned short* h4, unsigned short* l4, int e4,
                       const float* s5, unsigned short* h5, unsigned short* l5, int e5)
{
    int i = blockIdx.x * 256 + threadIdx.x;
    const float* s; unsigned short* h; unsigned short* l; int j;
    if (i < e0)      { s = s0; h = h0; l = l0; j = i; }
    else if (i < e1) { s = s1; h = h1; l = l1; j = i - e0; }
    else if (i < e2) { s = s2; h = h2; l = l2; j = i - e1; }
    else if (i < e3) { s = s3; h = h3; l = l3; j = i - e2; }
    else if (i < e4) { s = s4; h = h4; l = l4; j = i - e3; }
    else if (i < e5) { s = s5; h = h5; l = l5; j = i - e4; }
    else return;
    float4 v = ((const float4*)s)[j];
    ushort4 hh, ll;
    split2(v.x, hh.x, ll.x);
    split2(v.y, hh.y, ll.y);
    split2(v.z, hh.z, ll.z);
    split2(v.w, hh.w, ll.w);
    ((ushort4*)h)[j] = hh;
    ((ushort4*)l)[j] = ll;
}

// ---------------- setup / graph kernels ----------------

__global__ void init_k(int* count, int* needed, float* scal, int Nn)
{
    int i = blockIdx.x * 256 + threadIdx.x;
    if (i < Nn) { count[i] = 0; needed[i] = 0; }
    if (i < 8) scal[i] = 0.f;
}

// mark needed dst + scal[0]=sum(ew) + scal[1+h]=sum_c lew[h,c]*ae[h,c]
__global__ void markprep_k(const int* __restrict__ nidx, int* __restrict__ needed, int B,
                           const float* __restrict__ ew, int E,
                           const float* __restrict__ lew, const float* __restrict__ ae,
                           float* __restrict__ scal)
{
    int gid = blockIdx.x * 256 + threadIdx.x;
    if (gid < B) needed[nidx[gid]] = 1;
    float s = 0.f;
    for (int i = gid; i < E; i += gridDim.x * 256) s += ew[i];
    __shared__ float red[256];
    red[threadIdx.x] = s;
    __syncthreads();
    for (int off = 128; off; off >>= 1) {
        if (threadIdx.x < off) red[threadIdx.x] += red[threadIdx.x + off];
        __syncthreads();
    }
    if (threadIdx.x == 0) atomicAdd(&scal[0], red[0]);
    if (blockIdx.x == 0) {
        int w = threadIdx.x / 64, lane = threadIdx.x % 64;
        float c = 0.f;
        for (int cc = lane; cc < 256; cc += 64) c += lew[w * 256 + cc] * ae[w * 256 + cc];
        for (int off = 32; off; off >>= 1) c += __shfl_down(c, off);
        if (lane == 0) scal[1 + w] = c;
    }
}

__global__ void att_dots_k(const float* __restrict__ xp, const float* __restrict__ asrc_w,
                           const float* __restrict__ adst_w, float* __restrict__ a_src,
                           float* __restrict__ a_dst)
{
    int node = blockIdx.x;
    int w = threadIdx.x / 64, lane = threadIdx.x % 64;
    const float* row = xp + (size_t)node * 1024 + w * 256;
    float s1 = 0.f, s2 = 0.f;
#pragma unroll
    for (int c = lane; c < 256; c += 64) {
        float v = row[c];
        s1 += v * asrc_w[w * 256 + c];
        s2 += v * adst_w[w * 256 + c];
    }
    for (int off = 32; off; off >>= 1) { s1 += __shfl_down(s1, off); s2 += __shfl_down(s2, off); }
    if (lane == 0) { a_src[node * 4 + w] = s1; a_dst[node * 4 + w] = s2; }
}

__global__ void count_k(const int* __restrict__ ei, const int* __restrict__ needed,
                        int* __restrict__ count, int E, int Nn)
{
    int e = blockIdx.x * 256 + threadIdx.x;
    if (e >= E + Nn) return;
    int d = (e < E) ? ei[E + e] : e - E;
    if (needed[d]) atomicAdd(&count[d], 1);
}

// blocked one-pass exclusive scan (single block)
__global__ __launch_bounds__(1024) void scan_k(const int* __restrict__ count, int* __restrict__ offs, int Nn)
{
    __shared__ int sums[1024];
    int t = threadIdx.x;
    int C = (Nn + 1023) >> 10;
    int lo = t * C, hi = min(lo + C, Nn);
    int s = 0;
    for (int i = lo; i < hi; i++) s += count[i];
    sums[t] = s;
    __syncthreads();
    for (int off = 1; off < 1024; off <<= 1) {
        int add = (t >= off) ? sums[t - off] : 0;
        __syncthreads();
        sums[t] += add;
        __syncthreads();
    }
    int run = t ? sums[t - 1] : 0;
    for (int i = lo; i < hi; i++) { offs[i] = run; run += count[i]; }
}

__global__ void fill_k(const int* __restrict__ ei, const int* __restrict__ needed,
                       int* __restrict__ offs, int* __restrict__ eid, int E, int Nn)
{
    int e = blockIdx.x * 256 + threadIdx.x;
    if (e >= E + Nn) return;
    int d = (e < E) ? ei[E + e] : e - E;
    if (!needed[d]) return;
    int p = atomicAdd(&offs[d], 1);
    eid[p] = e;
}

// fused GAT softmax + aggregation; epilogue emits elu(out+gat_bias) pre-split to bf16 hi/lo
#define CH 256
__global__ __launch_bounds__(256)
void gat_agg_k(const int* __restrict__ ei, const float* __restrict__ ew,
               const float* __restrict__ scal, const float* __restrict__ a_src,
               const float* __restrict__ a_dst, const int* __restrict__ needed,
               const int* __restrict__ count, const int* __restrict__ offs_end,
               const int* __restrict__ eid, const float* __restrict__ xp,
               const float* __restrict__ gat_bias,
               unsigned short* __restrict__ aggh, unsigned short* __restrict__ aggl,
               int E, int Nn)
{
    int d = blockIdx.x;
    if (!needed[d]) return;
    int c = count[d];
    int start = offs_end[d] - c;
    int tid = threadIdx.x;
    __shared__ int   srcs[CH];
    __shared__ float al[CH * 4];
    __shared__ float mrun[4], drun[4], scale[4];
    if (tid < 4) { mrun[tid] = -1e30f; drun[tid] = 0.f; }
    float4 acc = make_float4(0.f, 0.f, 0.f, 0.f);
    const int h = tid >> 6;
    const int x = tid * 4;
    const float adst0 = a_dst[d * 4 + 0], adst1 = a_dst[d * 4 + 1],
                adst2 = a_dst[d * 4 + 2], adst3 = a_dst[d * 4 + 3];

    for (int cb = 0; cb < c; cb += CH) {
        int cc = min(CH, c - cb);
        __syncthreads();
        for (int t = tid; t < cc * 4; t += 256) {
            int j = t >> 2, hh = t & 3;
            int e = eid[start + cb + j];
            int s; float ea;
            if (e < E) { s = ei[e]; ea = ew[e]; }
            else       { s = e - E; ea = scal[0] / (float)E; }
            float ad = hh == 0 ? adst0 : hh == 1 ? adst1 : hh == 2 ? adst2 : adst3;
            float a = a_src[s * 4 + hh] + ad + ea * scal[1 + hh];
            a = a > 0.f ? a : 0.2f * a;
            al[j * 4 + hh] = a;
            if (hh == 0) srcs[j] = s;
        }
        __syncthreads();
        if (tid < 4) {
            float m = -1e30f;
            for (int j = 0; j < cc; j++) m = fmaxf(m, al[j * 4 + tid]);
            float nm = fmaxf(mrun[tid], m);
            float sc = expf(mrun[tid] - nm);
            scale[tid] = sc;
            drun[tid] *= sc;
            mrun[tid] = nm;
        }
        __syncthreads();
        for (int t = tid; t < cc * 4; t += 256) {
            int j = t >> 2, hh = t & 3;
            al[j * 4 + hh] = expf(al[j * 4 + hh] - mrun[hh]);
        }
        __syncthreads();
        if (tid < 4) {
            float s = 0.f;
            for (int j = 0; j < cc; j++) s += al[j * 4 + tid];
            drun[tid] += s;
        }
        float sc = scale[h];
        acc.x *= sc; acc.y *= sc; acc.z *= sc; acc.w *= sc;
        for (int j = 0; j < cc; j++) {
            float w = al[j * 4 + h];
            const float4 v = *(const float4*)(xp + (size_t)srcs[j] * 1024 + x);
            acc.x = fmaf(w, v.x, acc.x);
            acc.y = fmaf(w, v.y, acc.y);
            acc.z = fmaf(w, v.z, acc.z);
            acc.w = fmaf(w, v.w, acc.w);
        }
    }
    __syncthreads();
    float dn = drun[h];
    float4 gb = *(const float4*)(gat_bias + x);
    float t0 = acc.x / dn + gb.x, t1 = acc.y / dn + gb.y,
          t2 = acc.z / dn + gb.z, t3 = acc.w / dn + gb.w;
    t0 = t0 > 0.f ? t0 : expf(t0) - 1.f;
    t1 = t1 > 0.f ? t1 : expf(t1) - 1.f;
    t2 = t2 > 0.f ? t2 : expf(t2) - 1.f;
    t3 = t3 > 0.f ? t3 : expf(t3) - 1.f;
    ushort4 hh, ll;
    split2(t0, hh.x, ll.x);
    split2(t1, hh.y, ll.y);
    split2(t2, hh.z, ll.z);
    split2(t3, hh.w, ll.w);
    *(ushort4*)(aggh + (size_t)d * 1024 + x) = hh;
    *(ushort4*)(aggl + (size_t)d * 1024 + x) = ll;
}

__global__ void score_k(const float* __restrict__ s1, const float* __restrict__ sw2,
                        const float* __restrict__ sb2, float* __restrict__ out, int B)
{
    int b = blockIdx.x * 4 + threadIdx.x / 64;
    int lane = threadIdx.x % 64;
    if (b >= B) return;
    float4 v = *(const float4*)(s1 + (size_t)b * 256 + lane * 4);
    float4 w = *(const float4*)(sw2 + lane * 4);
    float s = v.x * w.x + v.y * w.y + v.z * w.z + v.w * w.w;
    for (int off = 32; off; off >>= 1) s += __shfl_down(s, off);
    if (lane == 0) out[b] = s + sb2[0];
}

// ---------------- launch ----------------

extern "C" void kernel_launch(void* const* d_in, const int* in_sizes, int n_in,
                              void* d_out, int out_size, void* d_ws, size_t ws_size,
                              hipStream_t stream)
{
    const float* sem      = (const float*)d_in[0];
    const float* gx       = (const float*)d_in[1];
    const int*   ei       = (const int*)d_in[2];
    const float* ew       = (const float*)d_in[3];
    const float* heur     = (const float*)d_in[4];
    const int*   nidx     = (const int*)d_in[5];
    const float* sem_w1   = (const float*)d_in[6];
    const float* sem_b1   = (const float*)d_in[7];
    const float* sem_w2   = (const float*)d_in[8];
    const float* sem_b2   = (const float*)d_in[9];
    const float* lin_w    = (const float*)d_in[10];
    const float* lin_edge = (const float*)d_in[11];
    const float* att_src  = (const float*)d_in[12];
    const float* att_dst  = (const float*)d_in[13];
    const float* att_edge = (const float*)d_in[14];
    const float* gat_bias = (const float*)d_in[15];
    const float* struct_w = (const float*)d_in[16];
    const float* struct_b = (const float*)d_in[17];
    const float* gate_w   = (const float*)d_in[18];
    const float* gate_b   = (const float*)d_in[19];
    const float* heur_w   = (const float*)d_in[20];
    const float* heur_b   = (const float*)d_in[21];
    const float* hwp      = (const float*)d_in[22];
    const float* sw1      = (const float*)d_in[23];
    const float* sb1      = (const float*)d_in[24];
    const float* sw2      = (const float*)d_in[25];
    const float* sb2      = (const float*)d_in[26];
    float* out = (float*)d_out;

    const int DIN = 768, HC = 1024, HID = 256;
    const int B  = in_sizes[0] / (2 * DIN);
    const int Nn = in_sizes[1] / DIN;
    const int E  = in_sizes[3];

    float* ws = (float*)d_ws;
    size_t off = 0;
    auto alloc = [&](size_t n) { float* p = ws + off; off += n; return p; };
    auto allocU = [&](size_t nelem) { return (unsigned short*)alloc((nelem + 1) / 2); };

    float* xp        = alloc((size_t)Nn * HC);           // x_proj f32 [N,1024]
    unsigned short* aggh = allocU((size_t)Nn * HC);      // elu(agg+bias) bf16 hi
    unsigned short* aggl = allocU((size_t)Nn * HC);
    float* h_sem    = alloc((size_t)B * HID);
    float* h_struct = alloc((size_t)B * HID);
    float* s1f      = alloc((size_t)B * HID);            // gelu(h_fused@sw1) f32
    unsigned short* s1h = allocU((size_t)B * HID);       // sem hidden split
    unsigned short* s1l = allocU((size_t)B * HID);
    unsigned short* gAh = allocU((size_t)B * 512);       // concat(h_sem,h_struct) split
    unsigned short* gAl = allocU((size_t)B * 512);
    unsigned short* fuh = allocU((size_t)B * HID);       // h_fused split
    unsigned short* ful = allocU((size_t)B * HID);
    float* a_src    = alloc((size_t)Nn * 4);
    float* a_dst    = alloc((size_t)Nn * 4);
    int* countb     = (int*)alloc((size_t)Nn);
    int* offsb      = (int*)alloc((size_t)Nn);
    int* neededb    = (int*)alloc((size_t)Nn);
    int* eidb       = (int*)alloc((size_t)(E + Nn));
    float* scal     = alloc(8);
    // weight bf16 hi/lo
    unsigned short* linw_h = allocU((size_t)HC * DIN);
    unsigned short* linw_l = allocU((size_t)HC * DIN);
    unsigned short* sw1w_h = allocU((size_t)HID * 2 * DIN);
    unsigned short* sw1w_l = allocU((size_t)HID * 2 * DIN);
    unsigned short* sw2w_h = allocU((size_t)HID * HID);
    unsigned short* sw2w_l = allocU((size_t)HID * HID);
    unsigned short* stw_h  = allocU((size_t)HID * HC);
    unsigned short* stw_l  = allocU((size_t)HID * HC);
    unsigned short* gaw_h  = allocU((size_t)HID * 512);
    unsigned short* gaw_l  = allocU((size_t)HID * 512);
    unsigned short* scw_h  = allocU((size_t)HID * HID);
    unsigned short* scw_l  = allocU((size_t)HID * HID);
    unsigned short* gxh    = allocU((size_t)Nn * DIN);
    unsigned short* gxl    = allocU((size_t)Nn * DIN);
    (void)ws_size; (void)n_in; (void)out_size;

    // --- setup: CSR + scalars ---
    init_k<<<(Nn + 255) / 256, 256, 0, stream>>>(countb, neededb, scal, Nn);
    markprep_k<<<256, 256, 0, stream>>>(nidx, neededb, B, ew, E, lin_edge, att_edge, scal);
    int tot = E + Nn;
    count_k<<<(tot + 255) / 256, 256, 0, stream>>>(ei, neededb, countb, E, Nn);
    scan_k<<<1, 1024, 0, stream>>>(countb, offsb, Nn);
    fill_k<<<(tot + 255) / 256, 256, 0, stream>>>(ei, neededb, offsb, eidb, E, Nn);

    // --- weight conversions (one launch) ---
    int c0 = (HC * DIN) / 4;                 // lin_w
    int c1 = c0 + (HID * 2 * DIN) / 4;       // sem_w1
    int c2 = c1 + (HID * HID) / 4;           // sem_w2
    int c3 = c2 + (HID * HC) / 4;            // struct_w
    int c4 = c3 + (HID * 512) / 4;           // gate_w
    int c5 = c4 + (HID * HID) / 4;           // sw1
    wcvt_k<<<(c5 + 255) / 256, 256, 0, stream>>>(
        lin_w, linw_h, linw_l, c0,
        sem_w1, sw1w_h, sw1w_l, c1,
        sem_w2, sw2w_h, sw2w_l, c2,
        struct_w, stw_h, stw_l, c3,
        gate_w, gaw_h, gaw_l, c4,
        sw1, scw_h, scw_l, c5);
    cvt_k<<<((Nn * DIN / 4) + 255) / 256, 256, 0, stream>>>(gx, gxh, gxl, Nn * DIN / 4);

    // head GEMM shape: 32x64 tile, grid (B/32)x(256/64) = 512 blocks (2/CU)
    const int nbh = HID / 64;                     // 4
    dim3 gh((B / 32) * nbh);                      // 512

    // --- semantic MLP: s1 = gelu(sem @ w1^T + b1) [f32 A, split out]; h_sem = s1 @ w2^T + b2 ---
    mgemm_k<1, 2, 2, 2, 1, 0, 1, 1><<<gh, 256, 0, stream>>>(
        nullptr, nullptr, sem, nullptr, sw1w_h, sw1w_l, sem_b1,
        nullptr, s1h, s1l, HID, 0, nullptr, nullptr, nullptr, nullptr, nullptr, nullptr,
        B, HID, 2 * DIN, nbh);
    mgemm_k<1, 2, 2, 2, 0, 0, 0, 2><<<gh, 256, 0, stream>>>(
        s1h, s1l, nullptr, nullptr, sw2w_h, sw2w_l, sem_b2,
        h_sem, gAh, gAl, 512, 0, nullptr, nullptr, nullptr, nullptr, nullptr, nullptr,
        B, HID, HID, nbh);

    // --- graph branch: x_proj (128x128 tile) ---
    const int nbx_x = HC / 128;                   // 8
    const int nby_x = (Nn + 127) / 128;           // 79
    mgemm_k<4, 4, 2, 2, 0, 0, 0, 0><<<nbx_x * nby_x, 256, 0, stream>>>(
        gxh, gxl, nullptr, nullptr, linw_h, linw_l, nullptr,
        xp, nullptr, nullptr, 0, 0, nullptr, nullptr, nullptr, nullptr, nullptr, nullptr,
        Nn, HC, DIN, nbx_x);
    att_dots_k<<<Nn, 256, 0, stream>>>(xp, att_src, att_dst, a_src, a_dst);
    gat_agg_k<<<Nn, 256, 0, stream>>>(ei, ew, scal, a_src, a_dst, neededb, countb, offsb, eidb,
                                      xp, gat_bias, aggh, aggl, E, Nn);

    // h_struct = gelu( gathered-elu-agg @ struct_w^T + struct_b ); also split into gateA[:,256:512]
    mgemm_k<1, 2, 2, 2, 1, 1, 0, 2><<<gh, 256, 0, stream>>>(
        aggh, aggl, nullptr, nidx, stw_h, stw_l, struct_b,
        h_struct, gAh, gAl, 512, 256, nullptr, nullptr, nullptr, nullptr, nullptr, nullptr,
        B, HID, HC, nbh);

    // gate GEMM with fused heur + fusion epilogue -> h_fused split
    mgemm_k<1, 2, 2, 2, 3, 0, 0, 1><<<gh, 256, 0, stream>>>(
        gAh, gAl, nullptr, nullptr, gaw_h, gaw_l, gate_b,
        nullptr, fuh, ful, HID, 0, h_sem, h_struct, heur, heur_w, heur_b, hwp,
        B, HID, 512, nbh);

    // s1 = gelu(h_fused @ sw1^T + sb1)
    mgemm_k<1, 2, 2, 2, 1, 0, 0, 0><<<gh, 256, 0, stream>>>(
        fuh, ful, nullptr, nullptr, scw_h, scw_l, sb1,
        s1f, nullptr, nullptr, 0, 0, nullptr, nullptr, nullptr, nullptr, nullptr, nullptr,
        B, HID, HID, nbh);

    score_k<<<B / 4, 256, 0, stream>>>(s1f, sw2, sb2, out, B);
}

// Round 6
// 232.689 us; speedup vs baseline: 7.7654x; 1.1149x over previous
//
#include <hip/hip_runtime.h>
#include <math.h>

#define DEV __device__ __forceinline__

typedef __attribute__((ext_vector_type(8))) short bf16x8;
typedef __attribute__((ext_vector_type(4))) float f32x4;

DEV float gelu_f(float x) { return 0.5f * x * (1.f + erff(x * 0.70710678118654752440f)); }

DEV unsigned short f2bf(float f) {
    unsigned u = __float_as_uint(f);
    u += 0x7FFF + ((u >> 16) & 1);
    return (unsigned short)(u >> 16);
}
DEV float bf2f(unsigned short h) { return __uint_as_float(((unsigned)h) << 16); }
DEV void split2(float v, unsigned short& h, unsigned short& l) {
    h = f2bf(v);
    l = f2bf(v - bf2f(h));
}

// async global->LDS, 16B per lane; LDS dest = wave-uniform base + lane*16 (linear)
DEV void gload_lds16(const void* g, void* l) {
    __builtin_amdgcn_global_load_lds((const __attribute__((address_space(1))) void*)g,
                                     (__attribute__((address_space(3))) void*)l, 16, 0, 0);
}

// ---------------- MFMA GEMM, LDS-staged; SPLIT=1: split-bf16 3-term (near-f32), SPLIT=0: plain bf16 ----------------
// C = act(A[M,K] @ W[N,K]^T + bias). BK=64, T2 XOR-swizzle (slot^row&7), T1 XCD swizzle.
// ASRC: 0 = A pre-split hi/lo (gload_lds); 1 = A f32, reg-stage + split + ds_write (SPLIT=1 only).
// GATHER: A row m -> gidx[m] (ASRC=0 only).
// EPI: 0 none, 1 exact GELU, 3 fused gate+heur+fusion.
// OUT: 0 = f32 C; 1 = split Ch/Cl; 2 = f32 C AND split Ch/Cl; 3 = bf16 Ch only. (Ch at [row*ldsp+coff+col])
template<int FM, int FN, int WR, int WC, int EPI, int GATHER, int ASRC, int OUT, int SPLIT>
__global__ __launch_bounds__(WR* WC * 64)
void mgemm_k(const unsigned short* __restrict__ Ah, const unsigned short* __restrict__ Al,
             const float* __restrict__ Af, const int* __restrict__ gidx,
             const unsigned short* __restrict__ Wh, const unsigned short* __restrict__ Wl,
             const float* __restrict__ bias,
             float* __restrict__ C, unsigned short* __restrict__ Ch, unsigned short* __restrict__ Cl,
             int ldsp, int coff,
             const float* __restrict__ fs_hsem, const float* __restrict__ fs_hstruct,
             const float* __restrict__ fs_heur, const float* __restrict__ fs_heurw,
             const float* __restrict__ fs_heurb, const float* __restrict__ fs_hw,
             int M, int N, int K, int nbx)
{
    constexpr int BM = WR * FM * 16, BN = WC * FN * 16;
    constexpr int NW = WR * WC;
    __shared__ alignas(16) unsigned short sAh[BM * 64];
    __shared__ alignas(16) unsigned short sWh[BN * 64];
    __shared__ alignas(16) unsigned short sAl[SPLIT ? BM * 64 : 8];
    __shared__ alignas(16) unsigned short sWl[SPLIT ? BN * 64 : 8];

    const int tid = threadIdx.x;
    const int lane = tid & 63;
    const int wid = tid >> 6;
    const int wr = wid / WC, wc = wid % WC;

    const int nwg = gridDim.x;
    int bid = blockIdx.x;
    int swz = ((nwg & 7) == 0) ? (bid & 7) * (nwg >> 3) + (bid >> 3) : bid;
    const int bx = swz % nbx, by = swz / nbx;
    const int row0 = by * BM;
    const int col0 = bx * BN;

    f32x4 acc[FM][FN];
#pragma unroll
    for (int i = 0; i < FM; i++)
#pragma unroll
        for (int j = 0; j < FN; j++) acc[i][j] = (f32x4){0.f, 0.f, 0.f, 0.f};

    const int srow = lane >> 3;   // row within an 8-row staging call
    const int sslot = lane & 7;   // 16B slot within the 128B row

    for (int k0 = 0; k0 < K; k0 += 64) {
        // --- stage A ---
#pragma unroll
        for (int c = 0; c < BM / 8 / NW; c++) {
            int call = c * NW + wid;
            int r = call * 8 + srow;
            int gr = row0 + r;
            gr = gr < M ? gr : M - 1;
            if (ASRC == 0) {
                if (GATHER) gr = gidx[gr];
                int b = (sslot ^ (r & 7)) << 4;
                gload_lds16((const char*)(Ah + (size_t)gr * K + k0) + b, (char*)sAh + call * 1024);
                if (SPLIT)
                    gload_lds16((const char*)(Al + (size_t)gr * K + k0) + b, (char*)sAl + call * 1024);
            } else {
                const float* sp = Af + (size_t)gr * K + k0 + sslot * 8;
                float vv[8];
                *(float4*)&vv[0] = *(const float4*)sp;
                *(float4*)&vv[4] = *(const float4*)(sp + 4);
                union { bf16x8 v; unsigned short u[8]; } ph, pl;
#pragma unroll
                for (int q = 0; q < 8; q++) split2(vv[q], ph.u[q], pl.u[q]);
                int b = (sslot ^ (r & 7)) << 4;
                *(bf16x8*)((char*)sAh + r * 128 + b) = ph.v;
                *(bf16x8*)((char*)sAl + r * 128 + b) = pl.v;
            }
        }
        // --- stage W ---
#pragma unroll
        for (int c = 0; c < BN / 8 / NW; c++) {
            int call = c * NW + wid;
            int r = call * 8 + srow;
            int gr = col0 + r;
            int b = (sslot ^ (r & 7)) << 4;
            gload_lds16((const char*)(Wh + (size_t)gr * K + k0) + b, (char*)sWh + call * 1024);
            if (SPLIT)
                gload_lds16((const char*)(Wl + (size_t)gr * K + k0) + b, (char*)sWl + call * 1024);
        }
        __syncthreads();

        const int fr = lane & 15, kq = lane >> 4;
#pragma unroll
        for (int ks = 0; ks < 2; ks++) {
            bf16x8 ah[FM], al[FM], bh[FN], bl[FN];
#pragma unroll
            for (int i = 0; i < FM; i++) {
                int r = wr * FM * 16 + i * 16 + fr;
                int b = ((ks * 4 + kq) ^ (r & 7)) << 4;
                ah[i] = *(const bf16x8*)((const char*)sAh + r * 128 + b);
                if (SPLIT) al[i] = *(const bf16x8*)((const char*)sAl + r * 128 + b);
            }
#pragma unroll
            for (int j = 0; j < FN; j++) {
                int r = wc * FN * 16 + j * 16 + fr;
                int b = ((ks * 4 + kq) ^ (r & 7)) << 4;
                bh[j] = *(const bf16x8*)((const char*)sWh + r * 128 + b);
                if (SPLIT) bl[j] = *(const bf16x8*)((const char*)sWl + r * 128 + b);
            }
#pragma unroll
            for (int i = 0; i < FM; i++)
#pragma unroll
                for (int j = 0; j < FN; j++) {
                    acc[i][j] = __builtin_amdgcn_mfma_f32_16x16x32_bf16(ah[i], bh[j], acc[i][j], 0, 0, 0);
                    if (SPLIT) {
                        acc[i][j] = __builtin_amdgcn_mfma_f32_16x16x32_bf16(al[i], bh[j], acc[i][j], 0, 0, 0);
                        acc[i][j] = __builtin_amdgcn_mfma_f32_16x16x32_bf16(ah[i], bl[j], acc[i][j], 0, 0, 0);
                    }
                }
        }
        __syncthreads();
    }

    const int fr = lane & 15;
    const int r0 = (lane >> 4) * 4;   // C/D: col = lane&15, row = (lane>>4)*4 + reg
#pragma unroll
    for (int i = 0; i < FM; i++) {
#pragma unroll
        for (int jj = 0; jj < 4; jj++) {
            int gr = row0 + wr * FM * 16 + i * 16 + r0 + jj;
            if (gr >= M) continue;
#pragma unroll
            for (int j = 0; j < FN; j++) {
                int gc = col0 + wc * FN * 16 + j * 16 + fr;
                float v = acc[i][j][jj] + (bias ? bias[gc] : 0.f);
                if (EPI == 1) v = gelu_f(v);
                else if (EPI == 3) {
                    float g = 1.f / (1.f + expf(-v));
                    float hh = fs_heurb[gc];
#pragma unroll
                    for (int q = 0; q < 6; q++) hh = fmaf(fs_heur[gr * 6 + q], fs_heurw[gc * 6 + q], hh);
                    hh = gelu_f(hh);
                    float hl = g * fs_hsem[(size_t)gr * 256 + gc] + (1.f - g) * fs_hstruct[(size_t)gr * 256 + gc];
                    float hwv = fs_hw[0];
                    v = hwv * hh + (1.f - hwv) * hl;
                }
                if (OUT == 0 || OUT == 2) C[(size_t)gr * N + gc] = v;
                if (OUT == 1 || OUT == 2) {
                    unsigned short h, l;
                    split2(v, h, l);
                    Ch[(size_t)gr * ldsp + coff + gc] = h;
                    Cl[(size_t)gr * ldsp + coff + gc] = l;
                }
                if (OUT == 3) Ch[(size_t)gr * ldsp + coff + gc] = f2bf(v);
            }
        }
    }
}

// ---------------- conversion kernels ----------------

// f32 -> bf16 (round-to-nearest), hi only
__global__ void cvt1_k(const float* __restrict__ src, unsigned short* __restrict__ hi, int n4)
{
    int i = blockIdx.x * 256 + threadIdx.x;
    if (i >= n4) return;
    float4 v = ((const float4*)src)[i];
    ushort4 h;
    h.x = f2bf(v.x); h.y = f2bf(v.y); h.z = f2bf(v.z); h.w = f2bf(v.w);
    ((ushort4*)hi)[i] = h;
}

// 6 weight buffers -> hi/lo in one launch; e0..e5 are CUMULATIVE float4 counts
__global__ void wcvt_k(const float* s0, unsigned short* h0, unsigned short* l0, int e0,
                       const float* s1, unsigned short* h1, unsigned short* l1, int e1,
                       const float* s2, unsigned short* h2, unsigned short* l2, int e2,
                       const float* s3, unsigned short* h3, unsigned short* l3, int e3,
                       const float* s4, unsigned short* h4, unsigned short* l4, int e4,
                       const float* s5, unsigned short* h5, unsigned short* l5, int e5)
{
    int i = blockIdx.x * 256 + threadIdx.x;
    const float* s; unsigned short* h; unsigned short* l; int j;
    if (i < e0)      { s = s0; h = h0; l = l0; j = i; }
    else if (i < e1) { s = s1; h = h1; l = l1; j = i - e0; }
    else if (i < e2) { s = s2; h = h2; l = l2; j = i - e1; }
    else if (i < e3) { s = s3; h = h3; l = l3; j = i - e2; }
    else if (i < e4) { s = s4; h = h4; l = l4; j = i - e3; }
    else if (i < e5) { s = s5; h = h5; l = l5; j = i - e4; }
    else return;
    float4 v = ((const float4*)s)[j];
    ushort4 hh, ll;
    split2(v.x, hh.x, ll.x);
    split2(v.y, hh.y, ll.y);
    split2(v.z, hh.z, ll.z);
    split2(v.w, hh.w, ll.w);
    ((ushort4*)h)[j] = hh;
    ((ushort4*)l)[j] = ll;
}

// ---------------- setup / graph kernels ----------------

__global__ void init_k(int* count, int* needed, float* scal, int Nn)
{
    int i = blockIdx.x * 256 + threadIdx.x;
    if (i < Nn) { count[i] = 0; needed[i] = 0; }
    if (i < 8) scal[i] = 0.f;
}

// mark needed dst + scal[0]=sum(ew) + scal[1+h]=sum_c lew[h,c]*ae[h,c]
__global__ void markprep_k(const int* __restrict__ nidx, int* __restrict__ needed, int B,
                           const float* __restrict__ ew, int E,
                           const float* __restrict__ lew, const float* __restrict__ ae,
                           float* __restrict__ scal)
{
    int gid = blockIdx.x * 256 + threadIdx.x;
    if (gid < B) needed[nidx[gid]] = 1;
    float s = 0.f;
    for (int i = gid; i < E; i += gridDim.x * 256) s += ew[i];
    __shared__ float red[256];
    red[threadIdx.x] = s;
    __syncthreads();
    for (int off = 128; off; off >>= 1) {
        if (threadIdx.x < off) red[threadIdx.x] += red[threadIdx.x + off];
        __syncthreads();
    }
    if (threadIdx.x == 0) atomicAdd(&scal[0], red[0]);
    if (blockIdx.x == 0) {
        int w = threadIdx.x / 64, lane = threadIdx.x % 64;
        float c = 0.f;
        for (int cc = lane; cc < 256; cc += 64) c += lew[w * 256 + cc] * ae[w * 256 + cc];
        for (int off = 32; off; off >>= 1) c += __shfl_down(c, off);
        if (lane == 0) scal[1 + w] = c;
    }
}

// rank-1 attention weights: wsrc[k*4+h] = sum_c lin_w[(h*256+c)*768+k]*att_src[h,c]; same wdst
__global__ void wprep_k(const float* __restrict__ lin_w, const float* __restrict__ att_src,
                        const float* __restrict__ att_dst,
                        float* __restrict__ wsrc, float* __restrict__ wdst)
{
    int gid = blockIdx.x * 256 + threadIdx.x;
    if (gid >= 4 * 768) return;
    int h = gid / 768, k = gid % 768;
    float ss = 0.f, sd = 0.f;
    for (int c = 0; c < 256; c++) {
        float w = lin_w[(size_t)(h * 256 + c) * 768 + k];
        ss = fmaf(w, att_src[h * 256 + c], ss);
        sd = fmaf(w, att_dst[h * 256 + c], sd);
    }
    wsrc[k * 4 + h] = ss;
    wdst[k * 4 + h] = sd;
}

// a_src[n,h] = gx[n,:] . wsrc[:,h] ; one wave per node
__global__ void adot_k(const unsigned short* __restrict__ gxh, const float* __restrict__ wsrc,
                       const float* __restrict__ wdst, float* __restrict__ a_src,
                       float* __restrict__ a_dst, int Nn)
{
    int node = blockIdx.x * 4 + (threadIdx.x >> 6);
    if (node >= Nn) return;
    int lane = threadIdx.x & 63;
    float s0 = 0.f, s1 = 0.f, s2 = 0.f, s3 = 0.f;
    float d0 = 0.f, d1 = 0.f, d2 = 0.f, d3 = 0.f;
    for (int k = lane; k < 768; k += 64) {
        float g = bf2f(gxh[(size_t)node * 768 + k]);
        float4 ws = *(const float4*)(wsrc + k * 4);
        float4 wd = *(const float4*)(wdst + k * 4);
        s0 = fmaf(g, ws.x, s0); s1 = fmaf(g, ws.y, s1);
        s2 = fmaf(g, ws.z, s2); s3 = fmaf(g, ws.w, s3);
        d0 = fmaf(g, wd.x, d0); d1 = fmaf(g, wd.y, d1);
        d2 = fmaf(g, wd.z, d2); d3 = fmaf(g, wd.w, d3);
    }
    for (int off = 32; off; off >>= 1) {
        s0 += __shfl_down(s0, off); s1 += __shfl_down(s1, off);
        s2 += __shfl_down(s2, off); s3 += __shfl_down(s3, off);
        d0 += __shfl_down(d0, off); d1 += __shfl_down(d1, off);
        d2 += __shfl_down(d2, off); d3 += __shfl_down(d3, off);
    }
    if (lane == 0) {
        a_src[node * 4 + 0] = s0; a_src[node * 4 + 1] = s1;
        a_src[node * 4 + 2] = s2; a_src[node * 4 + 3] = s3;
        a_dst[node * 4 + 0] = d0; a_dst[node * 4 + 1] = d1;
        a_dst[node * 4 + 2] = d2; a_dst[node * 4 + 3] = d3;
    }
}

__global__ void count_k(const int* __restrict__ ei, const int* __restrict__ needed,
                        int* __restrict__ count, int E, int Nn)
{
    int e = blockIdx.x * 256 + threadIdx.x;
    if (e >= E + Nn) return;
    int d = (e < E) ? ei[E + e] : e - E;
    if (needed[d]) atomicAdd(&count[d], 1);
}

// blocked one-pass exclusive scan (single block)
__global__ __launch_bounds__(1024) void scan_k(const int* __restrict__ count, int* __restrict__ offs, int Nn)
{
    __shared__ int sums[1024];
    int t = threadIdx.x;
    int C = (Nn + 1023) >> 10;
    int lo = t * C, hi = min(lo + C, Nn);
    int s = 0;
    for (int i = lo; i < hi; i++) s += count[i];
    sums[t] = s;
    __syncthreads();
    for (int off = 1; off < 1024; off <<= 1) {
        int add = (t >= off) ? sums[t - off] : 0;
        __syncthreads();
        sums[t] += add;
        __syncthreads();
    }
    int run = t ? sums[t - 1] : 0;
    for (int i = lo; i < hi; i++) { offs[i] = run; run += count[i]; }
}

__global__ void fill_k(const int* __restrict__ ei, const int* __restrict__ needed,
                       int* __restrict__ offs, int* __restrict__ eid, int E, int Nn)
{
    int e = blockIdx.x * 256 + threadIdx.x;
    if (e >= E + Nn) return;
    int d = (e < E) ? ei[E + e] : e - E;
    if (!needed[d]) return;
    int p = atomicAdd(&offs[d], 1);
    eid[p] = e;
}

// fused GAT softmax + aggregation; xp in bf16; epilogue emits elu(out+gat_bias) split to hi/lo
#define CH 256
__global__ __launch_bounds__(256)
void gat_agg_k(const int* __restrict__ ei, const float* __restrict__ ew,
               const float* __restrict__ scal, const float* __restrict__ a_src,
               const float* __restrict__ a_dst, const int* __restrict__ needed,
               const int* __restrict__ count, const int* __restrict__ offs_end,
               const int* __restrict__ eid, const unsigned short* __restrict__ xpb,
               const float* __restrict__ gat_bias,
               unsigned short* __restrict__ aggh, unsigned short* __restrict__ aggl,
               int E, int Nn)
{
    int d = blockIdx.x;
    if (!needed[d]) return;
    int c = count[d];
    int start = offs_end[d] - c;
    int tid = threadIdx.x;
    __shared__ int   srcs[CH];
    __shared__ float al[CH * 4];
    __shared__ float mrun[4], drun[4], scale[4];
    if (tid < 4) { mrun[tid] = -1e30f; drun[tid] = 0.f; }
    float4 acc = make_float4(0.f, 0.f, 0.f, 0.f);
    const int h = tid >> 6;
    const int x = tid * 4;
    const float adst0 = a_dst[d * 4 + 0], adst1 = a_dst[d * 4 + 1],
                adst2 = a_dst[d * 4 + 2], adst3 = a_dst[d * 4 + 3];

    for (int cb = 0; cb < c; cb += CH) {
        int cc = min(CH, c - cb);
        __syncthreads();
        for (int t = tid; t < cc * 4; t += 256) {
            int j = t >> 2, hh = t & 3;
            int e = eid[start + cb + j];
            int s; float ea;
            if (e < E) { s = ei[e]; ea = ew[e]; }
            else       { s = e - E; ea = scal[0] / (float)E; }
            float ad = hh == 0 ? adst0 : hh == 1 ? adst1 : hh == 2 ? adst2 : adst3;
            float a = a_src[s * 4 + hh] + ad + ea * scal[1 + hh];
            a = a > 0.f ? a : 0.2f * a;
            al[j * 4 + hh] = a;
            if (hh == 0) srcs[j] = s;
        }
        __syncthreads();
        if (tid < 4) {
            float m = -1e30f;
            for (int j = 0; j < cc; j++) m = fmaxf(m, al[j * 4 + tid]);
            float nm = fmaxf(mrun[tid], m);
            float sc = expf(mrun[tid] - nm);
            scale[tid] = sc;
            drun[tid] *= sc;
            mrun[tid] = nm;
        }
        __syncthreads();
        for (int t = tid; t < cc * 4; t += 256) {
            int j = t >> 2, hh = t & 3;
            al[j * 4 + hh] = expf(al[j * 4 + hh] - mrun[hh]);
        }
        __syncthreads();
        if (tid < 4) {
            float s = 0.f;
            for (int j = 0; j < cc; j++) s += al[j * 4 + tid];
            drun[tid] += s;
        }
        float sc = scale[h];
        acc.x *= sc; acc.y *= sc; acc.z *= sc; acc.w *= sc;
        for (int j = 0; j < cc; j++) {
            float w = al[j * 4 + h];
            ushort4 vv = *(const ushort4*)(xpb + (size_t)srcs[j] * 1024 + x);
            acc.x = fmaf(w, bf2f(vv.x), acc.x);
            acc.y = fmaf(w, bf2f(vv.y), acc.y);
            acc.z = fmaf(w, bf2f(vv.z), acc.z);
            acc.w = fmaf(w, bf2f(vv.w), acc.w);
        }
    }
    __syncthreads();
    float dn = drun[h];
    float4 gb = *(const float4*)(gat_bias + x);
    float t0 = acc.x / dn + gb.x, t1 = acc.y / dn + gb.y,
          t2 = acc.z / dn + gb.z, t3 = acc.w / dn + gb.w;
    t0 = t0 > 0.f ? t0 : expf(t0) - 1.f;
    t1 = t1 > 0.f ? t1 : expf(t1) - 1.f;
    t2 = t2 > 0.f ? t2 : expf(t2) - 1.f;
    t3 = t3 > 0.f ? t3 : expf(t3) - 1.f;
    ushort4 hh, ll;
    split2(t0, hh.x, ll.x);
    split2(t1, hh.y, ll.y);
    split2(t2, hh.z, ll.z);
    split2(t3, hh.w, ll.w);
    *(ushort4*)(aggh + (size_t)d * 1024 + x) = hh;
    *(ushort4*)(aggl + (size_t)d * 1024 + x) = ll;
}

__global__ void score_k(const float* __restrict__ s1, const float* __restrict__ sw2,
                        const float* __restrict__ sb2, float* __restrict__ out, int B)
{
    int b = blockIdx.x * 4 + threadIdx.x / 64;
    int lane = threadIdx.x % 64;
    if (b >= B) return;
    float4 v = *(const float4*)(s1 + (size_t)b * 256 + lane * 4);
    float4 w = *(const float4*)(sw2 + lane * 4);
    float s = v.x * w.x + v.y * w.y + v.z * w.z + v.w * w.w;
    for (int off = 32; off; off >>= 1) s += __shfl_down(s, off);
    if (lane == 0) out[b] = s + sb2[0];
}

// ---------------- launch ----------------

extern "C" void kernel_launch(void* const* d_in, const int* in_sizes, int n_in,
                              void* d_out, int out_size, void* d_ws, size_t ws_size,
                              hipStream_t stream)
{
    const float* sem      = (const float*)d_in[0];
    const float* gx       = (const float*)d_in[1];
    const int*   ei       = (const int*)d_in[2];
    const float* ew       = (const float*)d_in[3];
    const float* heur     = (const float*)d_in[4];
    const int*   nidx     = (const int*)d_in[5];
    const float* sem_w1   = (const float*)d_in[6];
    const float* sem_b1   = (const float*)d_in[7];
    const float* sem_w2   = (const float*)d_in[8];
    const float* sem_b2   = (const float*)d_in[9];
    const float* lin_w    = (const float*)d_in[10];
    const float* lin_edge = (const float*)d_in[11];
    const float* att_src  = (const float*)d_in[12];
    const float* att_dst  = (const float*)d_in[13];
    const float* att_edge = (const float*)d_in[14];
    const float* gat_bias = (const float*)d_in[15];
    const float* struct_w = (const float*)d_in[16];
    const float* struct_b = (const float*)d_in[17];
    const float* gate_w   = (const float*)d_in[18];
    const float* gate_b   = (const float*)d_in[19];
    const float* heur_w   = (const float*)d_in[20];
    const float* heur_b   = (const float*)d_in[21];
    const float* hwp      = (const float*)d_in[22];
    const float* sw1      = (const float*)d_in[23];
    const float* sb1      = (const float*)d_in[24];
    const float* sw2      = (const float*)d_in[25];
    const float* sb2      = (const float*)d_in[26];
    float* out = (float*)d_out;

    const int DIN = 768, HC = 1024, HID = 256;
    const int B  = in_sizes[0] / (2 * DIN);
    const int Nn = in_sizes[1] / DIN;
    const int E  = in_sizes[3];

    float* ws = (float*)d_ws;
    size_t off = 0;
    auto alloc = [&](size_t n) { float* p = ws + off; off += n; return p; };
    auto allocU = [&](size_t nelem) { return (unsigned short*)alloc((nelem + 1) / 2); };

    unsigned short* xpb  = allocU((size_t)Nn * HC);      // x_proj bf16 [N,1024]
    unsigned short* aggh = allocU((size_t)Nn * HC);      // elu(agg+bias) bf16 hi
    unsigned short* aggl = allocU((size_t)Nn * HC);
    float* h_sem    = alloc((size_t)B * HID);
    float* h_struct = alloc((size_t)B * HID);
    float* s1f      = alloc((size_t)B * HID);            // gelu(h_fused@sw1) f32
    unsigned short* s1h = allocU((size_t)B * HID);       // sem hidden split
    unsigned short* s1l = allocU((size_t)B * HID);
    unsigned short* gAh = allocU((size_t)B * 512);       // concat(h_sem,h_struct) split
    unsigned short* gAl = allocU((size_t)B * 512);
    unsigned short* fuh = allocU((size_t)B * HID);       // h_fused split
    unsigned short* ful = allocU((size_t)B * HID);
    float* a_src    = alloc((size_t)Nn * 4);
    float* a_dst    = alloc((size_t)Nn * 4);
    float* wsrc     = alloc((size_t)DIN * 4);
    float* wdst     = alloc((size_t)DIN * 4);
    int* countb     = (int*)alloc((size_t)Nn);
    int* offsb      = (int*)alloc((size_t)Nn);
    int* neededb    = (int*)alloc((size_t)Nn);
    int* eidb       = (int*)alloc((size_t)(E + Nn));
    float* scal     = alloc(8);
    // weight bf16 hi/lo
    unsigned short* linw_h = allocU((size_t)HC * DIN);
    unsigned short* linw_l = allocU((size_t)HC * DIN);   // unused by x_proj now (kept by wcvt layout)
    unsigned short* sw1w_h = allocU((size_t)HID * 2 * DIN);
    unsigned short* sw1w_l = allocU((size_t)HID * 2 * DIN);
    unsigned short* sw2w_h = allocU((size_t)HID * HID);
    unsigned short* sw2w_l = allocU((size_t)HID * HID);
    unsigned short* stw_h  = allocU((size_t)HID * HC);
    unsigned short* stw_l  = allocU((size_t)HID * HC);
    unsigned short* gaw_h  = allocU((size_t)HID * 512);
    unsigned short* gaw_l  = allocU((size_t)HID * 512);
    unsigned short* scw_h  = allocU((size_t)HID * HID);
    unsigned short* scw_l  = allocU((size_t)HID * HID);
    unsigned short* gxh    = allocU((size_t)Nn * DIN);
    (void)ws_size; (void)n_in; (void)out_size;

    // --- setup: CSR + scalars ---
    init_k<<<(Nn + 255) / 256, 256, 0, stream>>>(countb, neededb, scal, Nn);
    markprep_k<<<256, 256, 0, stream>>>(nidx, neededb, B, ew, E, lin_edge, att_edge, scal);
    int tot = E + Nn;
    count_k<<<(tot + 255) / 256, 256, 0, stream>>>(ei, neededb, countb, E, Nn);
    scan_k<<<1, 1024, 0, stream>>>(countb, offsb, Nn);
    fill_k<<<(tot + 255) / 256, 256, 0, stream>>>(ei, neededb, offsb, eidb, E, Nn);

    // --- weight conversions (one launch) + gx bf16 + rank-1 att weights ---
    int c0 = (HC * DIN) / 4;                 // lin_w
    int c1 = c0 + (HID * 2 * DIN) / 4;       // sem_w1
    int c2 = c1 + (HID * HID) / 4;           // sem_w2
    int c3 = c2 + (HID * HC) / 4;            // struct_w
    int c4 = c3 + (HID * 512) / 4;           // gate_w
    int c5 = c4 + (HID * HID) / 4;           // sw1
    wcvt_k<<<(c5 + 255) / 256, 256, 0, stream>>>(
        lin_w, linw_h, linw_l, c0,
        sem_w1, sw1w_h, sw1w_l, c1,
        sem_w2, sw2w_h, sw2w_l, c2,
        struct_w, stw_h, stw_l, c3,
        gate_w, gaw_h, gaw_l, c4,
        sw1, scw_h, scw_l, c5);
    cvt1_k<<<((Nn * DIN / 4) + 255) / 256, 256, 0, stream>>>(gx, gxh, Nn * DIN / 4);
    wprep_k<<<(4 * DIN + 255) / 256, 256, 0, stream>>>(lin_w, att_src, att_dst, wsrc, wdst);

    // head GEMM shape: 32x64 tile, grid (B/32)x(256/64) = 512 blocks
    const int nbh = HID / 64;                     // 4
    dim3 gh((B / 32) * nbh);                      // 512

    // --- semantic MLP: s1 = gelu(sem @ w1^T + b1) [f32 A, split out]; h_sem = s1 @ w2^T + b2 ---
    mgemm_k<1, 2, 2, 2, 1, 0, 1, 1, 1><<<gh, 256, 0, stream>>>(
        nullptr, nullptr, sem, nullptr, sw1w_h, sw1w_l, sem_b1,
        nullptr, s1h, s1l, HID, 0, nullptr, nullptr, nullptr, nullptr, nullptr, nullptr,
        B, HID, 2 * DIN, nbh);
    mgemm_k<1, 2, 2, 2, 0, 0, 0, 2, 1><<<gh, 256, 0, stream>>>(
        s1h, s1l, nullptr, nullptr, sw2w_h, sw2w_l, sem_b2,
        h_sem, gAh, gAl, 512, 0, nullptr, nullptr, nullptr, nullptr, nullptr, nullptr,
        B, HID, HID, nbh);

    // --- graph branch: x_proj plain bf16 (1 MFMA), bf16 out ---
    const int nbx_x = HC / 128;                   // 8
    const int nby_x = (Nn + 127) / 128;           // 79
    mgemm_k<4, 4, 2, 2, 0, 0, 0, 3, 0><<<nbx_x * nby_x, 256, 0, stream>>>(
        gxh, nullptr, nullptr, nullptr, linw_h, nullptr, nullptr,
        nullptr, xpb, nullptr, HC, 0, nullptr, nullptr, nullptr, nullptr, nullptr, nullptr,
        Nn, HC, DIN, nbx_x);
    adot_k<<<(Nn + 3) / 4, 256, 0, stream>>>(gxh, wsrc, wdst, a_src, a_dst, Nn);
    gat_agg_k<<<Nn, 256, 0, stream>>>(ei, ew, scal, a_src, a_dst, neededb, countb, offsb, eidb,
                                      xpb, gat_bias, aggh, aggl, E, Nn);

    // h_struct = gelu( gathered-elu-agg @ struct_w^T + struct_b ); also split into gateA[:,256:512]
    mgemm_k<1, 2, 2, 2, 1, 1, 0, 2, 1><<<gh, 256, 0, stream>>>(
        aggh, aggl, nullptr, nidx, stw_h, stw_l, struct_b,
        h_struct, gAh, gAl, 512, 256, nullptr, nullptr, nullptr, nullptr, nullptr, nullptr,
        B, HID, HC, nbh);

    // gate GEMM with fused heur + fusion epilogue -> h_fused split
    mgemm_k<1, 2, 2, 2, 3, 0, 0, 1, 1><<<gh, 256, 0, stream>>>(
        gAh, gAl, nullptr, nullptr, gaw_h, gaw_l, gate_b,
        nullptr, fuh, ful, HID, 0, h_sem, h_struct, heur, heur_w, heur_b, hwp,
        B, HID, 512, nbh);

    // s1 = gelu(h_fused @ sw1^T + sb1)
    mgemm_k<1, 2, 2, 2, 1, 0, 0, 0, 1><<<gh, 256, 0, stream>>>(
        fuh, ful, nullptr, nullptr, scw_h, scw_l, sb1,
        s1f, nullptr, nullptr, 0, 0, nullptr, nullptr, nullptr, nullptr, nullptr, nullptr,
        B, HID, HID, nbh);

    score_k<<<B / 4, 256, 0, stream>>>(s1f, sw2, sb2, out, B);
}